// Round 11
// baseline (258.357 us; speedup 1.0000x reference)
//
#include <hip/hip_runtime.h>
#include <hip/hip_bf16.h>

using bf16 = __hip_bfloat16;
typedef unsigned int u32x4 __attribute__((ext_vector_type(4)));
typedef float f32x4 __attribute__((ext_vector_type(4)));
typedef __bf16 bf16x8 __attribute__((ext_vector_type(8)));

#define DEVI __device__ __forceinline__

DEVI f32x4 mfma16(u32x4 a, u32x4 b, f32x4 c) {
    return __builtin_amdgcn_mfma_f32_16x16x32_bf16(
        __builtin_bit_cast(bf16x8, a), __builtin_bit_cast(bf16x8, b), c, 0, 0, 0);
}

// async global->LDS DMA, 16B per lane; LDS dest = uniform base + lane*16
DEVI void gload16(const bf16* g, bf16* l) {
    __builtin_amdgcn_global_load_lds(
        (const __attribute__((address_space(1))) unsigned int*)g,
        (__attribute__((address_space(3))) unsigned int*)l,
        16, 0, 0);
}

struct bf8 { bf16 h[8]; };
struct f2 { float x, y; };

DEVI u32x4 pack8(f32x4 lo, f32x4 hi) {
    bf8 t;
#pragma unroll
    for (int i = 0; i < 4; i++) {
        t.h[i] = __float2bfloat16(lo[i]);
        t.h[4 + i] = __float2bfloat16(hi[i]);
    }
    return __builtin_bit_cast(u32x4, t);
}

// RNE-packed 4x bf16 -> 64-bit
DEVI unsigned long long pk4(float a, float b, float c, float d) {
    union { unsigned long long u; bf16 h[4]; } t;
    t.h[0] = __float2bfloat16(a); t.h[1] = __float2bfloat16(b);
    t.h[2] = __float2bfloat16(c); t.h[3] = __float2bfloat16(d);
    return t.u;
}

// truncating bf16x2 pack (1 op)
DEVI unsigned trunc2(float a, float b) {
    return __builtin_amdgcn_perm(__builtin_bit_cast(unsigned, b),
                                 __builtin_bit_cast(unsigned, a), 0x07060302);
}

// ------------- prep: WT[n][k] = (bf16)W[k][n] (5 mats) + xb = (bf16)x --------
__global__ __launch_bounds__(256) void prep(
    const float* __restrict__ Wq, const float* __restrict__ Wk,
    const float* __restrict__ Wv, const float* __restrict__ W1,
    const float* __restrict__ W2, const float* __restrict__ x,
    bf16* __restrict__ WT, bf16* __restrict__ xb)
{
    int b = blockIdx.x;
    if (b < 5120) {
        int w = b >> 10;
        const float* src = (w == 0) ? Wq : (w == 1) ? Wk : (w == 2) ? Wv : (w == 3) ? W1 : W2;
        int idx = (b & 1023) * 256 + threadIdx.x;   // idx = n*512 + k
        int n = idx >> 9, kk = idx & 511;
        WT[(size_t)w * 262144 + idx] = __float2bfloat16(src[kk * 512 + n]);
    } else {
        size_t i = ((size_t)(b - 5120) * 256 + threadIdx.x) * 8;
        f32x4 lo = *(const f32x4*)&x[i];
        f32x4 hi = *(const f32x4*)&x[i + 4];
        *(u32x4*)&xb[i] = pack8(lo, hi);
    }
}

// ------------- GEMM cores: global_load_lds staging, XOR-swizzled LDS ---------
// LDS LINEAR (gload_lds writes lane-linear; padding forbidden). Conflict-free
// via XOR swizzle applied BOTH sides (rule 21):
//   write: per-lane global col = ((lane&7) ^ (lane>>3))*8
//   read : col ^= (lm&7)*8    (row&7 == lm&7 for every fragment row)
// DISCIPLINE (rounds 2-4,8 post-mortems):
//   * one body per kernel; no min-waves launch_bounds arg; no explicit LDS dbuf
#define GEMM_BODY(EPILOGUE)                                                          \
    __shared__ __align__(16) bf16 As[128 * 64];                                      \
    __shared__ __align__(16) bf16 Bs[128 * 64];                                      \
    const int tid = threadIdx.x;                                                     \
    const int lane = tid & 63, wave = tid >> 6;                                      \
    const int wm = (wave >> 1) * 64, wn = (wave & 1) * 64;                           \
    const int lm = lane & 15, lq = lane >> 4;                                        \
    const int cxor = (lm & 7) * 8;                                                   \
    const int srow = wave * 32 + (lane >> 3);                                        \
    const int scol = ((lane & 7) ^ (lane >> 3)) * 8;                                 \
    const bf16* Ag = A + (size_t)(bm + srow) * 512 + scol;                           \
    const bf16* Bg = Bt + (size_t)(bn + srow) * 512 + scol;                          \
    bf16* Al = &As[wave * 32 * 64];                                                  \
    bf16* Bl = &Bs[wave * 32 * 64];                                                  \
    f32x4 acc[4][4];                                                                 \
    _Pragma("unroll") for (int i = 0; i < 4; i++)                                    \
        _Pragma("unroll") for (int j = 0; j < 4; j++)                                \
            acc[i][j] = (f32x4){0.f, 0.f, 0.f, 0.f};                                 \
    for (int k0 = 0; k0 < 512; k0 += 64) {                                           \
        __syncthreads();                                                             \
        _Pragma("unroll") for (int p = 0; p < 4; p++) {                              \
            gload16(Ag + (size_t)p * 8 * 512 + k0, Al + p * 512);                    \
            gload16(Bg + (size_t)p * 8 * 512 + k0, Bl + p * 512);                    \
        }                                                                            \
        __syncthreads();                                                             \
        _Pragma("unroll") for (int h = 0; h < 2; h++) {                              \
            u32x4 af[4], bfr[4];                                                     \
            _Pragma("unroll") for (int i = 0; i < 4; i++)                            \
                af[i] = *(const u32x4*)&As[(wm + i * 16 + lm) * 64 + ((h * 32 + lq * 8) ^ cxor)]; \
            _Pragma("unroll") for (int j = 0; j < 4; j++)                            \
                bfr[j] = *(const u32x4*)&Bs[(wn + j * 16 + lm) * 64 + ((h * 32 + lq * 8) ^ cxor)]; \
            EPILOGUE##_MMA                                                           \
        }                                                                            \
    }

#define SWAPPED_MMA                                                                  \
    _Pragma("unroll") for (int i = 0; i < 4; i++)                                    \
        _Pragma("unroll") for (int j = 0; j < 4; j++)                                \
            acc[i][j] = mfma16(bfr[j], af[i], acc[i][j]);

#define GEMM_BODY_N64(EPILOGUE)                                                      \
    __shared__ __align__(16) bf16 As[128 * 64];                                      \
    __shared__ __align__(16) bf16 Bs[64 * 64];                                       \
    const int tid = threadIdx.x;                                                     \
    const int lane = tid & 63, wave = tid >> 6;                                      \
    const int wm = wave * 32;                                                        \
    const int lm = lane & 15, lq = lane >> 4;                                        \
    const int cxor = (lm & 7) * 8;                                                   \
    const int sr8 = lane >> 3;                                                       \
    const int scol = ((lane & 7) ^ sr8) * 8;                                         \
    const bf16* Ag = A + (size_t)(bm + wave * 32 + sr8) * 512 + scol;                \
    const bf16* Bg = Bt + (size_t)(bn + wave * 16 + sr8) * 512 + scol;               \
    bf16* Al = &As[wave * 32 * 64];                                                  \
    bf16* Bl = &Bs[wave * 16 * 64];                                                  \
    f32x4 acc[2][4];                                                                 \
    _Pragma("unroll") for (int i = 0; i < 2; i++)                                    \
        _Pragma("unroll") for (int j = 0; j < 4; j++)                                \
            acc[i][j] = (f32x4){0.f, 0.f, 0.f, 0.f};                                 \
    for (int k0 = 0; k0 < 512; k0 += 64) {                                           \
        __syncthreads();                                                             \
        _Pragma("unroll") for (int p = 0; p < 4; p++)                                \
            gload16(Ag + (size_t)p * 8 * 512 + k0, Al + p * 512);                    \
        _Pragma("unroll") for (int p = 0; p < 2; p++)                                \
            gload16(Bg + (size_t)p * 8 * 512 + k0, Bl + p * 512);                    \
        __syncthreads();                                                             \
        _Pragma("unroll") for (int h = 0; h < 2; h++) {                              \
            u32x4 af[2], bfr[4];                                                     \
            _Pragma("unroll") for (int i = 0; i < 2; i++)                            \
                af[i] = *(const u32x4*)&As[(wm + i * 16 + lm) * 64 + ((h * 32 + lq * 8) ^ cxor)]; \
            _Pragma("unroll") for (int j = 0; j < 4; j++)                            \
                bfr[j] = *(const u32x4*)&Bs[(j * 16 + lm) * 64 + ((h * 32 + lq * 8) ^ cxor)]; \
            EPILOGUE##_MMA_N64                                                       \
        }                                                                            \
    }

#define SWAPPED_MMA_N64                                                              \
    _Pragma("unroll") for (int i = 0; i < 2; i++)                                    \
        _Pragma("unroll") for (int j = 0; j < 4; j++)                                \
            acc[i][j] = mfma16(bfr[j], af[i], acc[i][j]);
#define NORMAL_MMA_N64                                                               \
    _Pragma("unroll") for (int i = 0; i < 2; i++)                                    \
        _Pragma("unroll") for (int j = 0; j < 4; j++)                                \
            acc[i][j] = mfma16(af[i], bfr[j], acc[i][j]);

// ------------- Q/K GEMM (swapped orientation), 128x128, 4 blk/CU -------------
__global__ __launch_bounds__(256) void gemm_qk(
    const bf16* __restrict__ A, const bf16* __restrict__ WT,
    const float* __restrict__ bqp, const float* __restrict__ bkp,
    bf16* __restrict__ qb, bf16* __restrict__ kb)
{
    const int wsel = blockIdx.y >> 2;                  // 0=q 1=k
    const int bm = blockIdx.x * 128, bn = (blockIdx.y & 3) * 128;
    const bf16* Bt = WT + (size_t)wsel * 262144;
    const float* bias = (wsel == 0) ? bqp : bkp;
    const float scale = (wsel == 0) ? 0.18033688f : 1.0f;   // log2e/8 into q
    bf16* dst = (wsel == 0) ? qb : kb;

    GEMM_BODY(SWAPPED)
#pragma unroll
    for (int i = 0; i < 4; i++) {
#pragma unroll
        for (int j = 0; j < 4; j++) {
            int row = bm + wm + i * 16 + lm;
            int colb = bn + wn + j * 16 + lq * 4;
            f32x4 b4 = *(const f32x4*)&bias[colb];
            *(unsigned long long*)&dst[(size_t)row * 512 + colb] =
                pk4((acc[i][j][0] + b4[0]) * scale, (acc[i][j][1] + b4[1]) * scale,
                    (acc[i][j][2] + b4[2]) * scale, (acc[i][j][3] + b4[3]) * scale);
        }
    }
}

// ------------- V GEMM (normal orientation) -> vT pack, 128x64 tile -----------
// vT key permutation (consumed by attn PV as the MFMA k-slot order):
//   within each 32-key block, key u = 16h + 4a + t  (h:1b, a:2b, t:2b)
//   is stored at column cc = 8a + 4h + t.
__global__ __launch_bounds__(256) void gemm_v(
    const bf16* __restrict__ A, const bf16* __restrict__ WT,
    const float* __restrict__ bvp, bf16* __restrict__ vT)
{
    const int bm = blockIdx.x * 128, bn = blockIdx.y * 64;
    const bf16* Bt = WT + (size_t)2 * 262144;
    const float* bias = bvp;

    GEMM_BODY_N64(NORMAL)
#pragma unroll
    for (int i = 0; i < 2; i++) {
#pragma unroll
        for (int j = 0; j < 4; j++) {
            int col = bn + j * 16 + lm;
            float bv = bias[col];
            int rowb = bm + wm + i * 16 + lq * 4;   // 4 consecutive nodes (mult of 4)
            int btq = rowb >> 10, node = rowb & 1023;
            int u = node & 31;                      // u&3 == 0 always
            int nodeP = (node & ~31) | (((u >> 2) & 3) << 3) | (((u >> 4) & 1) << 2);
            *(unsigned long long*)&vT[((size_t)((btq * 8 + (col >> 6)) * 64 + (col & 63))) * 1024 + nodeP] =
                pk4(acc[i][j][0] + bv, acc[i][j][1] + bv,
                    acc[i][j][2] + bv, acc[i][j][3] + bv);
        }
    }
}

// ------------- FFN GEMM (RELU or plain), swapped, 128x64 tile ----------------
template <bool RELU>
__global__ __launch_bounds__(256) void gemm_bt(
    const bf16* __restrict__ A, const bf16* __restrict__ Bt,
    const float* __restrict__ bias, bf16* __restrict__ C)
{
    const int bm = blockIdx.x * 128, bn = blockIdx.y * 64;
    GEMM_BODY_N64(SWAPPED)
#pragma unroll
    for (int i = 0; i < 2; i++) {
#pragma unroll
        for (int j = 0; j < 4; j++) {
            int row = bm + wm + i * 16 + lm;
            int colb = bn + j * 16 + lq * 4;
            f32x4 b4 = *(const f32x4*)&bias[colb];
            float c0 = acc[i][j][0] + b4[0], c1 = acc[i][j][1] + b4[1];
            float c2 = acc[i][j][2] + b4[2], c3 = acc[i][j][3] + b4[3];
            if (RELU) {
                c0 = fmaxf(c0, 0.f); c1 = fmaxf(c1, 0.f);
                c2 = fmaxf(c2, 0.f); c3 = fmaxf(c3, 0.f);
            }
            *(unsigned long long*)&C[(size_t)row * 512 + colb] = pk4(c0, c1, c2, c3);
        }
    }
}

// ------------- fused flash attention + residual LayerNorm --------------------
// Grid (16 bt, 32 qtiles of 32 rows), 512 threads = 8 waves, wave = head.
// Each wave: 32 q-rows x d=64 of ITS head (register-P, O^T = V^T P^T, ones-row
// denominator — unchanged math from the split attn kernel). All 8 heads of the
// same 32 rows live in one block, so the row LayerNorm of (o + x) completes
// in-block: per-lane partials -> shfl over lq -> 2KB LDS cross-wave reduce
// (reusing dead Ks). Writes vl bf16 directly; o f32 buffer + ln#1 kernel gone.
// K staged [32 keys][512] XOR-swizzled both sides (write col (lane^w)*8, read
// col ^ (lm&7)*8; row&7 == w on write, == lm&7 on read). V staged per-head
// [8][64][32] (vT keys already permuted within 32-blocks; KVBLK=32 aligns).
// LDS 64 KB -> 2 blocks/CU = 16 waves/CU. vl aliases qb: each block reads q
// and writes vl for exactly its own rows (disjoint across blocks) — safe.
__global__ __launch_bounds__(512) void attn_ln(
    const bf16* __restrict__ q, const bf16* __restrict__ k,
    const bf16* __restrict__ vT, const float* __restrict__ x,
    const float* __restrict__ lng, const float* __restrict__ lnb,
    bf16* __restrict__ vl)
{
    __shared__ __align__(16) bf16 Ks[32 * 512];    // [key][col ^ (key&7)*8]
    __shared__ __align__(16) bf16 Vs[8 * 64 * 32]; // [head][d][perm-key]

    const int tid = threadIdx.x, lane = tid & 63, w = tid >> 6;   // w = head
    const int bt = blockIdx.x;
    const int lm = lane & 15, lq = lane >> 4;
    const int qrow0 = bt * 1024 + blockIdx.y * 32;
    const int swz = (lm & 7) * 8;

    u32x4 qf[2][2];
#pragma unroll
    for (int tm = 0; tm < 2; tm++)
#pragma unroll
        for (int kk2 = 0; kk2 < 2; kk2++)
            qf[tm][kk2] = *(const u32x4*)&q[(size_t)(qrow0 + tm * 16 + lm) * 512 + w * 64 + kk2 * 32 + lq * 8];

    // staging sources (wave w, round p): K row p*8+w, pre-XOR col (lane^w)*8;
    // V head p*2+(w>>2), d=(w&3)*16+(lane>>2), key (lane&3)*8
    const bf16* kp = k + (size_t)(bt * 1024 + w) * 512 + ((lane ^ w) * 8);
    const bf16* vp = vT + ((size_t)((bt * 8 + (w >> 2)) * 64 + (w & 3) * 16 + (lane >> 2))) * 1024 + (lane & 3) * 8;
    bf16* kl = &Ks[w * 512];
    bf16* vld = &Vs[w * 512];

    const unsigned ow = (lm == 0) ? 0x3F803F80u : 0u;
    const u32x4 onesA = (u32x4){ow, ow, ow, ow};

    f32x4 accO[4][2];   // [d-tile][q-tile], O^T orientation
#pragma unroll
    for (int md = 0; md < 4; md++)
#pragma unroll
        for (int tm = 0; tm < 2; tm++) accO[md][tm] = (f32x4){0.f, 0.f, 0.f, 0.f};
    f32x4 accL[2] = {(f32x4){0.f, 0.f, 0.f, 0.f}, (f32x4){0.f, 0.f, 0.f, 0.f}};

    for (int kt = 0; kt < 32; kt++) {
        __syncthreads();   // all reads of previous tile done
#pragma unroll
        for (int p = 0; p < 4; p++) {
            gload16(kp + (size_t)kt * 16384 + p * 4096, kl + p * 4096);
            gload16(vp + kt * 32 + (size_t)p * 131072, vld + p * 4096);
        }
        __syncthreads();   // drain -> tile visible

        // S^T: A=K (m=key), B=Q (n=q); rows lm and 16+lm share row&7 == lm&7
        u32x4 kf00 = *(const u32x4*)&Ks[(size_t)lm * 512 + w * 64 + ((lq * 8) ^ swz)];
        u32x4 kf01 = *(const u32x4*)&Ks[(size_t)lm * 512 + w * 64 + ((32 + lq * 8) ^ swz)];
        u32x4 kf10 = *(const u32x4*)&Ks[(size_t)(16 + lm) * 512 + w * 64 + ((lq * 8) ^ swz)];
        u32x4 kf11 = *(const u32x4*)&Ks[(size_t)(16 + lm) * 512 + w * 64 + ((32 + lq * 8) ^ swz)];
        u32x4 pw[2];
#pragma unroll
        for (int tm = 0; tm < 2; tm++) {
            f32x4 s0 = (f32x4){0.f, 0.f, 0.f, 0.f};
            s0 = mfma16(kf00, qf[tm][0], s0);
            s0 = mfma16(kf01, qf[tm][1], s0);
            f32x4 s1 = (f32x4){0.f, 0.f, 0.f, 0.f};
            s1 = mfma16(kf10, qf[tm][0], s1);
            s1 = mfma16(kf11, qf[tm][1], s1);
            float p0 = __builtin_amdgcn_exp2f(s0[0]);
            float p1 = __builtin_amdgcn_exp2f(s0[1]);
            float p2 = __builtin_amdgcn_exp2f(s0[2]);
            float p3 = __builtin_amdgcn_exp2f(s0[3]);
            float p4 = __builtin_amdgcn_exp2f(s1[0]);
            float p5 = __builtin_amdgcn_exp2f(s1[1]);
            float p6 = __builtin_amdgcn_exp2f(s1[2]);
            float p7 = __builtin_amdgcn_exp2f(s1[3]);
            // slots 0-3 = keys lq*4+r of sub-tile 0; 4-7 = sub-tile 1
            pw[tm] = (u32x4){trunc2(p0, p1), trunc2(p2, p3),
                             trunc2(p4, p5), trunc2(p6, p7)};
        }
        // denominator via ones-row MFMA (off the VALU)
        accL[0] = mfma16(onesA, pw[0], accL[0]);
        accL[1] = mfma16(onesA, pw[1], accL[1]);
        __builtin_amdgcn_s_setprio(1);
#pragma unroll
        for (int md = 0; md < 4; md++) {
            u32x4 vf = *(const u32x4*)&Vs[w * 2048 + (md * 16 + lm) * 32 + lq * 8];
            accO[md][0] = mfma16(vf, pw[0], accO[md][0]);
            accO[md][1] = mfma16(vf, pw[1], accO[md][1]);
        }
        __builtin_amdgcn_s_setprio(0);
    }

    // ---- epilogue: o = accO/l ; t = o + x ; LN over full 512-row in-block ----
    float sP[2], s2P[2];
#pragma unroll
    for (int tm = 0; tm < 2; tm++) {
        float l = accL[tm][0];
        l += __shfl_xor(l, 16);
        l += __shfl_xor(l, 32);
        float linv = 1.0f / l;
        float s = 0.f, s2 = 0.f;
#pragma unroll
        for (int md = 0; md < 4; md++) {
            f32x4 xv = *(const f32x4*)&x[(size_t)(qrow0 + tm * 16 + lm) * 512 + w * 64 + md * 16 + lq * 4];
            f32x4 t;
#pragma unroll
            for (int i = 0; i < 4; i++) {
                t[i] = accO[md][tm][i] * linv + xv[i];
                s += t[i];
                s2 += t[i] * t[i];
            }
            accO[md][tm] = t;
        }
        s += __shfl_xor(s, 16);  s += __shfl_xor(s, 32);
        s2 += __shfl_xor(s2, 16); s2 += __shfl_xor(s2, 32);
        sP[tm] = s; s2P[tm] = s2;
    }
    __syncthreads();                 // Ks dead -> reuse for cross-wave reduce
    f2* sred = (f2*)Ks;              // [8 waves][2 tm][16 lm], 2 KB
    if (lq == 0) {
        sred[(w * 2 + 0) * 16 + lm] = f2{sP[0], s2P[0]};
        sred[(w * 2 + 1) * 16 + lm] = f2{sP[1], s2P[1]};
    }
    __syncthreads();
#pragma unroll
    for (int tm = 0; tm < 2; tm++) {
        float S = 0.f, S2 = 0.f;
#pragma unroll
        for (int wj = 0; wj < 8; wj++) {
            f2 v = sred[(wj * 2 + tm) * 16 + lm];
            S += v.x; S2 += v.y;
        }
        float mean = S * (1.f / 512.f);
        float var = S2 * (1.f / 512.f) - mean * mean;
        float rstd = rsqrtf(var + 1e-5f);
#pragma unroll
        for (int md = 0; md < 4; md++) {
            int colb = w * 64 + md * 16 + lq * 4;
            f32x4 g4 = *(const f32x4*)&lng[colb];
            f32x4 b4 = *(const f32x4*)&lnb[colb];
            f32x4 t = accO[md][tm];
            *(unsigned long long*)&vl[(size_t)(qrow0 + tm * 16 + lm) * 512 + colb] =
                pk4((t[0] - mean) * rstd * g4[0] + b4[0],
                    (t[1] - mean) * rstd * g4[1] + b4[1],
                    (t[2] - mean) * rstd * g4[2] + b4[2],
                    (t[3] - mean) * rstd * g4[3] + b4[3]);
        }
    }
}

// ------------- LayerNorm (one wave per 512-el row) — final LN only -----------
template <bool AF32, bool RES, bool OF32>
__global__ __launch_bounds__(256) void ln_kernel(
    const void* __restrict__ a, const float* __restrict__ res,
    const float* __restrict__ g, const float* __restrict__ bb, void* __restrict__ out)
{
    int row = blockIdx.x * 4 + (threadIdx.x >> 6);
    int lane = threadIdx.x & 63;
    size_t base = (size_t)row * 512 + lane * 8;
    int cbase = lane * 8;

    float x8[8];
    if (AF32) {
        const float* af = (const float*)a;
        f32x4 lo = *(const f32x4*)&af[base];
        f32x4 hi = *(const f32x4*)&af[base + 4];
#pragma unroll
        for (int i = 0; i < 4; i++) { x8[i] = lo[i]; x8[4 + i] = hi[i]; }
    } else {
        bf8 av = __builtin_bit_cast(bf8, *(const u32x4*)&((const bf16*)a)[base]);
#pragma unroll
        for (int i = 0; i < 8; i++) x8[i] = __bfloat162float(av.h[i]);
    }
    if (RES) {
        f32x4 lo = *(const f32x4*)&res[base];
        f32x4 hi = *(const f32x4*)&res[base + 4];
#pragma unroll
        for (int i = 0; i < 4; i++) { x8[i] += lo[i]; x8[4 + i] += hi[i]; }
    }

    float s = 0.f, s2 = 0.f;
#pragma unroll
    for (int i = 0; i < 8; i++) { s += x8[i]; s2 += x8[i] * x8[i]; }
#pragma unroll
    for (int off = 1; off < 64; off <<= 1) {
        s += __shfl_xor(s, off);
        s2 += __shfl_xor(s2, off);
    }
    float mean = s * (1.f / 512.f);
    float var = s2 * (1.f / 512.f) - mean * mean;
    float rstd = rsqrtf(var + 1e-5f);

    f32x4 g0 = *(const f32x4*)&g[cbase], g1 = *(const f32x4*)&g[cbase + 4];
    f32x4 b0 = *(const f32x4*)&bb[cbase], b1v = *(const f32x4*)&bb[cbase + 4];
    float y[8];
#pragma unroll
    for (int i = 0; i < 4; i++) {
        y[i] = (x8[i] - mean) * rstd * g0[i] + b0[i];
        y[4 + i] = (x8[4 + i] - mean) * rstd * g1[i] + b1v[i];
    }
    if (OF32) {
        float* op = (float*)out;
        *(f32x4*)&op[base] = (f32x4){y[0], y[1], y[2], y[3]};
        *(f32x4*)&op[base + 4] = (f32x4){y[4], y[5], y[6], y[7]};
    } else {
        bf8 ov;
#pragma unroll
        for (int i = 0; i < 8; i++) ov.h[i] = __float2bfloat16(y[i]);
        *(u32x4*)&((bf16*)out)[base] = __builtin_bit_cast(u32x4, ov);
    }
}

// ------------- launch --------------------------------------------------------
extern "C" void kernel_launch(void* const* d_in, const int* in_sizes, int n_in,
                              void* d_out, int out_size, void* d_ws, size_t ws_size,
                              hipStream_t stream)
{
    const float* x    = (const float*)d_in[0];
    const float* Wq   = (const float*)d_in[1];
    const float* bq   = (const float*)d_in[2];
    const float* Wk   = (const float*)d_in[3];
    const float* bk   = (const float*)d_in[4];
    const float* Wv   = (const float*)d_in[5];
    const float* bv   = (const float*)d_in[6];
    const float* ln_g = (const float*)d_in[7];
    const float* ln_b = (const float*)d_in[8];
    const float* W1   = (const float*)d_in[9];
    const float* b1   = (const float*)d_in[10];
    const float* W2   = (const float*)d_in[11];
    const float* b2   = (const float*)d_in[12];
    const float* lnffg = (const float*)d_in[13];
    const float* lnffb = (const float*)d_in[14];
    float* out = (float*)d_out;

    bf16* ws = (bf16*)d_ws;
    bf16* WT = ws;                        // 5 * 262144 bf16
    bf16* qb = ws + 5 * 262144;           // 8388608 bf16 each below
    bf16* kb = qb + 8388608;
    bf16* vT = kb + 8388608;
    bf16* vl = qb;                        // alias q: attn_ln reads q rows then
                                          // writes vl same rows (disjoint across blocks)
    bf16* f1 = kb;                        // reuse (k dead after attention)
    bf16* f2 = vT;                        // reuse (v dead after attention)
    bf16* xb = (bf16*)d_out;              // scratch in d_out; final ln overwrites

    prep<<<9216, 256, 0, stream>>>(Wq, Wk, Wv, W1, W2, x, WT, xb);

    gemm_qk<<<dim3(128, 8), 256, 0, stream>>>(xb, WT, bq, bk, qb, kb);
    gemm_v <<<dim3(128, 8), 256, 0, stream>>>(xb, WT, bv, vT);

    attn_ln<<<dim3(16, 32), 512, 0, stream>>>(qb, kb, vT, x, ln_g, ln_b, vl);

    dim3 gg(128, 8);
    gemm_bt<true> <<<gg, 256, 0, stream>>>(vl, WT + 3 * 262144, b1, f1);
    gemm_bt<false><<<gg, 256, 0, stream>>>(f1, WT + 4 * 262144, b2, f2);

    ln_kernel<false, false, true><<<4096, 256, 0, stream>>>(f2, nullptr, lnffg, lnffb, out);
}

// Round 12
// 257.838 us; speedup vs baseline: 1.0020x; 1.0020x over previous
//
#include <hip/hip_runtime.h>
#include <hip/hip_bf16.h>

using bf16 = __hip_bfloat16;
typedef unsigned int u32x4 __attribute__((ext_vector_type(4)));
typedef float f32x4 __attribute__((ext_vector_type(4)));
typedef __bf16 bf16x8 __attribute__((ext_vector_type(8)));

#define DEVI __device__ __forceinline__

DEVI f32x4 mfma16(u32x4 a, u32x4 b, f32x4 c) {
    return __builtin_amdgcn_mfma_f32_16x16x32_bf16(
        __builtin_bit_cast(bf16x8, a), __builtin_bit_cast(bf16x8, b), c, 0, 0, 0);
}

// async global->LDS DMA, 16B per lane; LDS dest = uniform base + lane*16
DEVI void gload16(const bf16* g, bf16* l) {
    __builtin_amdgcn_global_load_lds(
        (const __attribute__((address_space(1))) unsigned int*)g,
        (__attribute__((address_space(3))) unsigned int*)l,
        16, 0, 0);
}

struct bf8 { bf16 h[8]; };

DEVI u32x4 pack8(f32x4 lo, f32x4 hi) {
    bf8 t;
#pragma unroll
    for (int i = 0; i < 4; i++) {
        t.h[i] = __float2bfloat16(lo[i]);
        t.h[4 + i] = __float2bfloat16(hi[i]);
    }
    return __builtin_bit_cast(u32x4, t);
}

// RNE-packed 4x bf16 -> 64-bit
DEVI unsigned long long pk4(float a, float b, float c, float d) {
    union { unsigned long long u; bf16 h[4]; } t;
    t.h[0] = __float2bfloat16(a); t.h[1] = __float2bfloat16(b);
    t.h[2] = __float2bfloat16(c); t.h[3] = __float2bfloat16(d);
    return t.u;
}

// truncating bf16x2 pack (1 op)
DEVI unsigned trunc2(float a, float b) {
    return __builtin_amdgcn_perm(__builtin_bit_cast(unsigned, b),
                                 __builtin_bit_cast(unsigned, a), 0x07060302);
}

// ------------- prep: WT[n][k] = (bf16)W[k][n] (5 mats) + xb = (bf16)x --------
__global__ __launch_bounds__(256) void prep(
    const float* __restrict__ Wq, const float* __restrict__ Wk,
    const float* __restrict__ Wv, const float* __restrict__ W1,
    const float* __restrict__ W2, const float* __restrict__ x,
    bf16* __restrict__ WT, bf16* __restrict__ xb)
{
    int b = blockIdx.x;
    if (b < 5120) {
        int w = b >> 10;
        const float* src = (w == 0) ? Wq : (w == 1) ? Wk : (w == 2) ? Wv : (w == 3) ? W1 : W2;
        int idx = (b & 1023) * 256 + threadIdx.x;   // idx = n*512 + k
        int n = idx >> 9, kk = idx & 511;
        WT[(size_t)w * 262144 + idx] = __float2bfloat16(src[kk * 512 + n]);
    } else {
        size_t i = ((size_t)(b - 5120) * 256 + threadIdx.x) * 8;
        f32x4 lo = *(const f32x4*)&x[i];
        f32x4 hi = *(const f32x4*)&x[i + 4];
        *(u32x4*)&xb[i] = pack8(lo, hi);
    }
}

// ------------- GEMM cores: global_load_lds staging, XOR-swizzled LDS ---------
// LDS LINEAR (gload_lds writes lane-linear; padding forbidden). Conflict-free
// via XOR swizzle applied BOTH sides (rule 21):
//   write: per-lane global col = ((lane&7) ^ (lane>>3))*8
//   read : col ^= (lm&7)*8    (row&7 == lm&7 for every fragment row)
// DISCIPLINE (rounds 2-4,8,11 post-mortems):
//   * one body per kernel; no min-waves launch_bounds arg; no explicit LDS dbuf
//   * do NOT fuse LN into attn (round 11: staging amortization drops 4x)
#define GEMM_BODY(EPILOGUE)                                                          \
    __shared__ __align__(16) bf16 As[128 * 64];                                      \
    __shared__ __align__(16) bf16 Bs[128 * 64];                                      \
    const int tid = threadIdx.x;                                                     \
    const int lane = tid & 63, wave = tid >> 6;                                      \
    const int wm = (wave >> 1) * 64, wn = (wave & 1) * 64;                           \
    const int lm = lane & 15, lq = lane >> 4;                                        \
    const int cxor = (lm & 7) * 8;                                                   \
    const int srow = wave * 32 + (lane >> 3);                                        \
    const int scol = ((lane & 7) ^ (lane >> 3)) * 8;                                 \
    const bf16* Ag = A + (size_t)(bm + srow) * 512 + scol;                           \
    const bf16* Bg = Bt + (size_t)(bn + srow) * 512 + scol;                          \
    bf16* Al = &As[wave * 32 * 64];                                                  \
    bf16* Bl = &Bs[wave * 32 * 64];                                                  \
    f32x4 acc[4][4];                                                                 \
    _Pragma("unroll") for (int i = 0; i < 4; i++)                                    \
        _Pragma("unroll") for (int j = 0; j < 4; j++)                                \
            acc[i][j] = (f32x4){0.f, 0.f, 0.f, 0.f};                                 \
    for (int k0 = 0; k0 < 512; k0 += 64) {                                           \
        __syncthreads();                                                             \
        _Pragma("unroll") for (int p = 0; p < 4; p++) {                              \
            gload16(Ag + (size_t)p * 8 * 512 + k0, Al + p * 512);                    \
            gload16(Bg + (size_t)p * 8 * 512 + k0, Bl + p * 512);                    \
        }                                                                            \
        __syncthreads();                                                             \
        _Pragma("unroll") for (int h = 0; h < 2; h++) {                              \
            u32x4 af[4], bfr[4];                                                     \
            _Pragma("unroll") for (int i = 0; i < 4; i++)                            \
                af[i] = *(const u32x4*)&As[(wm + i * 16 + lm) * 64 + ((h * 32 + lq * 8) ^ cxor)]; \
            _Pragma("unroll") for (int j = 0; j < 4; j++)                            \
                bfr[j] = *(const u32x4*)&Bs[(wn + j * 16 + lm) * 64 + ((h * 32 + lq * 8) ^ cxor)]; \
            EPILOGUE##_MMA                                                           \
        }                                                                            \
    }

#define SWAPPED_MMA                                                                  \
    _Pragma("unroll") for (int i = 0; i < 4; i++)                                    \
        _Pragma("unroll") for (int j = 0; j < 4; j++)                                \
            acc[i][j] = mfma16(bfr[j], af[i], acc[i][j]);

#define GEMM_BODY_N64(EPILOGUE)                                                      \
    __shared__ __align__(16) bf16 As[128 * 64];                                      \
    __shared__ __align__(16) bf16 Bs[64 * 64];                                       \
    const int tid = threadIdx.x;                                                     \
    const int lane = tid & 63, wave = tid >> 6;                                      \
    const int wm = wave * 32;                                                        \
    const int lm = lane & 15, lq = lane >> 4;                                        \
    const int cxor = (lm & 7) * 8;                                                   \
    const int sr8 = lane >> 3;                                                       \
    const int scol = ((lane & 7) ^ sr8) * 8;                                         \
    const bf16* Ag = A + (size_t)(bm + wave * 32 + sr8) * 512 + scol;                \
    const bf16* Bg = Bt + (size_t)(bn + wave * 16 + sr8) * 512 + scol;               \
    bf16* Al = &As[wave * 32 * 64];                                                  \
    bf16* Bl = &Bs[wave * 16 * 64];                                                  \
    f32x4 acc[2][4];                                                                 \
    _Pragma("unroll") for (int i = 0; i < 2; i++)                                    \
        _Pragma("unroll") for (int j = 0; j < 4; j++)                                \
            acc[i][j] = (f32x4){0.f, 0.f, 0.f, 0.f};                                 \
    for (int k0 = 0; k0 < 512; k0 += 64) {                                           \
        __syncthreads();                                                             \
        _Pragma("unroll") for (int p = 0; p < 4; p++)                                \
            gload16(Ag + (size_t)p * 8 * 512 + k0, Al + p * 512);                    \
        _Pragma("unroll") for (int p = 0; p < 2; p++)                                \
            gload16(Bg + (size_t)p * 8 * 512 + k0, Bl + p * 512);                    \
        __syncthreads();                                                             \
        _Pragma("unroll") for (int h = 0; h < 2; h++) {                              \
            u32x4 af[2], bfr[4];                                                     \
            _Pragma("unroll") for (int i = 0; i < 2; i++)                            \
                af[i] = *(const u32x4*)&As[(wm + i * 16 + lm) * 64 + ((h * 32 + lq * 8) ^ cxor)]; \
            _Pragma("unroll") for (int j = 0; j < 4; j++)                            \
                bfr[j] = *(const u32x4*)&Bs[(j * 16 + lm) * 64 + ((h * 32 + lq * 8) ^ cxor)]; \
            EPILOGUE##_MMA_N64                                                       \
        }                                                                            \
    }

#define SWAPPED_MMA_N64                                                              \
    _Pragma("unroll") for (int i = 0; i < 2; i++)                                    \
        _Pragma("unroll") for (int j = 0; j < 4; j++)                                \
            acc[i][j] = mfma16(bfr[j], af[i], acc[i][j]);
#define NORMAL_MMA_N64                                                               \
    _Pragma("unroll") for (int i = 0; i < 2; i++)                                    \
        _Pragma("unroll") for (int j = 0; j < 4; j++)                                \
            acc[i][j] = mfma16(af[i], bfr[j], acc[i][j]);

// ------------- Q/K GEMM (swapped orientation), 128x128, 4 blk/CU -------------
__global__ __launch_bounds__(256) void gemm_qk(
    const bf16* __restrict__ A, const bf16* __restrict__ WT,
    const float* __restrict__ bqp, const float* __restrict__ bkp,
    bf16* __restrict__ qb, bf16* __restrict__ kb)
{
    const int wsel = blockIdx.y >> 2;                  // 0=q 1=k
    const int bm = blockIdx.x * 128, bn = (blockIdx.y & 3) * 128;
    const bf16* Bt = WT + (size_t)wsel * 262144;
    const float* bias = (wsel == 0) ? bqp : bkp;
    const float scale = (wsel == 0) ? 0.18033688f : 1.0f;   // log2e/8 into q
    bf16* dst = (wsel == 0) ? qb : kb;

    GEMM_BODY(SWAPPED)
#pragma unroll
    for (int i = 0; i < 4; i++) {
#pragma unroll
        for (int j = 0; j < 4; j++) {
            int row = bm + wm + i * 16 + lm;
            int colb = bn + wn + j * 16 + lq * 4;
            f32x4 b4 = *(const f32x4*)&bias[colb];
            *(unsigned long long*)&dst[(size_t)row * 512 + colb] =
                pk4((acc[i][j][0] + b4[0]) * scale, (acc[i][j][1] + b4[1]) * scale,
                    (acc[i][j][2] + b4[2]) * scale, (acc[i][j][3] + b4[3]) * scale);
        }
    }
}

// ------------- V GEMM (normal orientation) -> vT pack, 128x64 tile -----------
// vT key permutation (consumed by attn PV as the MFMA k-slot order):
//   within each 32-key block, key u = 16h + 4a + t  (h:1b, a:2b, t:2b)
//   is stored at column cc = 8a + 4h + t.
__global__ __launch_bounds__(256) void gemm_v(
    const bf16* __restrict__ A, const bf16* __restrict__ WT,
    const float* __restrict__ bvp, bf16* __restrict__ vT)
{
    const int bm = blockIdx.x * 128, bn = blockIdx.y * 64;
    const bf16* Bt = WT + (size_t)2 * 262144;
    const float* bias = bvp;

    GEMM_BODY_N64(NORMAL)
#pragma unroll
    for (int i = 0; i < 2; i++) {
#pragma unroll
        for (int j = 0; j < 4; j++) {
            int col = bn + j * 16 + lm;
            float bv = bias[col];
            int rowb = bm + wm + i * 16 + lq * 4;   // 4 consecutive nodes (mult of 4)
            int btq = rowb >> 10, node = rowb & 1023;
            int u = node & 31;                      // u&3 == 0 always
            int nodeP = (node & ~31) | (((u >> 2) & 3) << 3) | (((u >> 4) & 1) << 2);
            *(unsigned long long*)&vT[((size_t)((btq * 8 + (col >> 6)) * 64 + (col & 63))) * 1024 + nodeP] =
                pk4(acc[i][j][0] + bv, acc[i][j][1] + bv,
                    acc[i][j][2] + bv, acc[i][j][3] + bv);
        }
    }
}

// ------------- FFN GEMM (RELU or plain), swapped, 128x64 tile ----------------
template <bool RELU>
__global__ __launch_bounds__(256) void gemm_bt(
    const bf16* __restrict__ A, const bf16* __restrict__ Bt,
    const float* __restrict__ bias, bf16* __restrict__ C)
{
    const int bm = blockIdx.x * 128, bn = blockIdx.y * 64;
    GEMM_BODY_N64(SWAPPED)
#pragma unroll
    for (int i = 0; i < 2; i++) {
#pragma unroll
        for (int j = 0; j < 4; j++) {
            int row = bm + wm + i * 16 + lm;
            int colb = bn + j * 16 + lq * 4;
            f32x4 b4 = *(const f32x4*)&bias[colb];
            float c0 = acc[i][j][0] + b4[0], c1 = acc[i][j][1] + b4[1];
            float c2 = acc[i][j][2] + b4[2], c3 = acc[i][j][3] + b4[3];
            if (RELU) {
                c0 = fmaxf(c0, 0.f); c1 = fmaxf(c1, 0.f);
                c2 = fmaxf(c2, 0.f); c3 = fmaxf(c3, 0.f);
            }
            *(unsigned long long*)&C[(size_t)row * 512 + colb] = pk4(c0, c1, c2, c3);
        }
    }
}

// ------------- flash attention: register-P, O^T = V^T * P^T ------------------
// q (pre-scaled by log2e/8), k: [16384 x 512] bf16
// vT: [(g)*64+d][1024] bf16, keys PERMUTED within 32-blocks (see gemm_v).
// o: [16384 x 512] f32.  grid(128 groups, 16 qtiles of 64 rows), 256 threads.
//
// Round-11 lesson: LDS footprint caps waves/SIMD. SINGLE-buffered K/V
// (18,432 B) + 64-row q-tiles (2048 blocks = 8 blocks/CU) gives 8 waves/SIMD
// (VGPR ~60) — double the latency hiding for the serial S->exp2->pack->PV
// chain. 2 barriers/tile; the drain is covered by cross-block overlap
// (8 independent block phases/CU), same mechanism as the GEMMs.
__global__ __launch_bounds__(256, 4) void attn_kernel(
    const bf16* __restrict__ q, const bf16* __restrict__ k,
    const bf16* __restrict__ vT, float* __restrict__ o)
{
    constexpr int KP = 72;   // 144 B stride: 16-B aligned, free 2-way
    constexpr int VP = 72;
    __shared__ __align__(16) bf16 Ks[64 * KP];        // [key][d]   single buffer
    __shared__ __align__(16) bf16 Vs[64 * VP];        // [d][perm-key]

    const int tid = threadIdx.x, lane = tid & 63, wave = tid >> 6;
    const int group = blockIdx.x;          // bt*8 + h
    const int bt = group >> 3, hh = group & 7;
    const int lm = lane & 15, lq = lane >> 4;
    const int qrow0 = bt * 1024 + blockIdx.y * 64 + wave * 16;   // 16 rows/wave

    u32x4 qf[2];
#pragma unroll
    for (int kk2 = 0; kk2 < 2; kk2++)
        qf[kk2] = *(const u32x4*)&q[(size_t)(qrow0 + lm) * 512 + hh * 64 + kk2 * 32 + lq * 8];

    const bf16* kbase = k + (size_t)(bt * 1024) * 512 + hh * 64;   // + row*512 + e
    const bf16* vbase = vT + (size_t)group * 64 * 1024;            // + d*1024 + key

    // staging coords (per thread, 2 chunks of 64-el rows)
    const int r0 = tid >> 3, e0 = (tid & 7) * 8;
    const int r1 = (256 + tid) >> 3;

    // ones A-fragment: A[row 0][k]=1.0 for all k, other rows 0
    const unsigned ow = (lm == 0) ? 0x3F803F80u : 0u;
    const u32x4 onesA = (u32x4){ow, ow, ow, ow};

    f32x4 accO[4];   // [d-tile], O^T orientation (16 q-cols = lm)
#pragma unroll
    for (int md = 0; md < 4; md++) accO[md] = (f32x4){0.f, 0.f, 0.f, 0.f};
    f32x4 accL = (f32x4){0.f, 0.f, 0.f, 0.f};

    // prefetch kt=0
    u32x4 kreg0 = *(const u32x4*)&kbase[(size_t)r0 * 512 + e0];
    u32x4 kreg1 = *(const u32x4*)&kbase[(size_t)r1 * 512 + e0];
    u32x4 vreg0 = *(const u32x4*)&vbase[(size_t)r0 * 1024 + e0];
    u32x4 vreg1 = *(const u32x4*)&vbase[(size_t)r1 * 1024 + e0];

    for (int kt = 0; kt < 16; kt++) {
        __syncthreads();   // all waves done computing previous tile
        *(u32x4*)&Ks[r0 * KP + e0] = kreg0;
        *(u32x4*)&Ks[r1 * KP + e0] = kreg1;
        *(u32x4*)&Vs[r0 * VP + e0] = vreg0;
        *(u32x4*)&Vs[r1 * VP + e0] = vreg1;
        __syncthreads();   // staged tile visible
        if (kt < 15) {     // prefetch into regs: in flight across compute
            const bf16* kn = kbase + (size_t)((kt + 1) * 64) * 512;
            const bf16* vn = vbase + (kt + 1) * 64;
            kreg0 = *(const u32x4*)&kn[(size_t)r0 * 512 + e0];
            kreg1 = *(const u32x4*)&kn[(size_t)r1 * 512 + e0];
            vreg0 = *(const u32x4*)&vn[(size_t)r0 * 1024 + e0];
            vreg1 = *(const u32x4*)&vn[(size_t)r1 * 1024 + e0];
        }

#pragma unroll
        for (int kc = 0; kc < 2; kc++) {
            const int t0 = kc * 2;
            // S^T tiles for this 32-key contraction: A=K (m=key), B=Q (n=q)
            u32x4 kf00 = *(const u32x4*)&Ks[(t0 * 16 + lm) * KP + lq * 8];
            u32x4 kf01 = *(const u32x4*)&Ks[(t0 * 16 + lm) * KP + 32 + lq * 8];
            u32x4 kf10 = *(const u32x4*)&Ks[((t0 + 1) * 16 + lm) * KP + lq * 8];
            u32x4 kf11 = *(const u32x4*)&Ks[((t0 + 1) * 16 + lm) * KP + 32 + lq * 8];
            f32x4 s0 = (f32x4){0.f, 0.f, 0.f, 0.f};
            s0 = mfma16(kf00, qf[0], s0);
            s0 = mfma16(kf01, qf[1], s0);
            f32x4 s1 = (f32x4){0.f, 0.f, 0.f, 0.f};
            s1 = mfma16(kf10, qf[0], s1);
            s1 = mfma16(kf11, qf[1], s1);
            float p0 = __builtin_amdgcn_exp2f(s0[0]);
            float p1 = __builtin_amdgcn_exp2f(s0[1]);
            float p2 = __builtin_amdgcn_exp2f(s0[2]);
            float p3 = __builtin_amdgcn_exp2f(s0[3]);
            float p4 = __builtin_amdgcn_exp2f(s1[0]);
            float p5 = __builtin_amdgcn_exp2f(s1[1]);
            float p6 = __builtin_amdgcn_exp2f(s1[2]);
            float p7 = __builtin_amdgcn_exp2f(s1[3]);
            // slots 0-3 = tile t0 keys lq*4+r ; slots 4-7 = tile t0+1
            u32x4 pw = (u32x4){trunc2(p0, p1), trunc2(p2, p3),
                               trunc2(p4, p5), trunc2(p6, p7)};
            // denominator: l += sum_k P (ones-row MFMA, off the VALU)
            accL = mfma16(onesA, pw, accL);
            // O^T += V^T * P^T : A = V^T from Vs (perm keys match pw slots)
            __builtin_amdgcn_s_setprio(1);
#pragma unroll
            for (int md = 0; md < 4; md++) {
                u32x4 vf = *(const u32x4*)&Vs[(md * 16 + lm) * VP + kc * 32 + lq * 8];
                accO[md] = mfma16(vf, pw, accO[md]);
            }
            __builtin_amdgcn_s_setprio(0);
        }
    }

    // l lives in reg0 of lanes lq==0; xor-reduce over lq broadcasts to all.
    float l = accL[0];
    l += __shfl_xor(l, 16);
    l += __shfl_xor(l, 32);
    float linv = 1.0f / l;
#pragma unroll
    for (int md = 0; md < 4; md++) {
        f32x4 r;
#pragma unroll
        for (int i = 0; i < 4; i++) r[i] = accO[md][i] * linv;
        // row = q (lm), cols = hh*64 + md*16 + lq*4 .. +3 (16B store)
        *(f32x4*)&o[(size_t)(qrow0 + lm) * 512 + hh * 64 + md * 16 + lq * 4] = r;
    }
}

// ------------- LayerNorm (one wave per 512-el row) ---------------------------
template <bool AF32, bool RES, bool OF32>
__global__ __launch_bounds__(256) void ln_kernel(
    const void* __restrict__ a, const float* __restrict__ res,
    const float* __restrict__ g, const float* __restrict__ bb, void* __restrict__ out)
{
    int row = blockIdx.x * 4 + (threadIdx.x >> 6);
    int lane = threadIdx.x & 63;
    size_t base = (size_t)row * 512 + lane * 8;
    int cbase = lane * 8;

    float x8[8];
    if (AF32) {
        const float* af = (const float*)a;
        f32x4 lo = *(const f32x4*)&af[base];
        f32x4 hi = *(const f32x4*)&af[base + 4];
#pragma unroll
        for (int i = 0; i < 4; i++) { x8[i] = lo[i]; x8[4 + i] = hi[i]; }
    } else {
        bf8 av = __builtin_bit_cast(bf8, *(const u32x4*)&((const bf16*)a)[base]);
#pragma unroll
        for (int i = 0; i < 8; i++) x8[i] = __bfloat162float(av.h[i]);
    }
    if (RES) {
        f32x4 lo = *(const f32x4*)&res[base];
        f32x4 hi = *(const f32x4*)&res[base + 4];
#pragma unroll
        for (int i = 0; i < 4; i++) { x8[i] += lo[i]; x8[4 + i] += hi[i]; }
    }

    float s = 0.f, s2 = 0.f;
#pragma unroll
    for (int i = 0; i < 8; i++) { s += x8[i]; s2 += x8[i] * x8[i]; }
#pragma unroll
    for (int off = 1; off < 64; off <<= 1) {
        s += __shfl_xor(s, off);
        s2 += __shfl_xor(s2, off);
    }
    float mean = s * (1.f / 512.f);
    float var = s2 * (1.f / 512.f) - mean * mean;
    float rstd = rsqrtf(var + 1e-5f);

    f32x4 g0 = *(const f32x4*)&g[cbase], g1 = *(const f32x4*)&g[cbase + 4];
    f32x4 b0 = *(const f32x4*)&bb[cbase], b1v = *(const f32x4*)&bb[cbase + 4];
    float y[8];
#pragma unroll
    for (int i = 0; i < 4; i++) {
        y[i] = (x8[i] - mean) * rstd * g0[i] + b0[i];
        y[4 + i] = (x8[4 + i] - mean) * rstd * g1[i] + b1v[i];
    }
    if (OF32) {
        float* op = (float*)out;
        *(f32x4*)&op[base] = (f32x4){y[0], y[1], y[2], y[3]};
        *(f32x4*)&op[base + 4] = (f32x4){y[4], y[5], y[6], y[7]};
    } else {
        bf8 ov;
#pragma unroll
        for (int i = 0; i < 8; i++) ov.h[i] = __float2bfloat16(y[i]);
        *(u32x4*)&((bf16*)out)[base] = __builtin_bit_cast(u32x4, ov);
    }
}

// ------------- launch --------------------------------------------------------
extern "C" void kernel_launch(void* const* d_in, const int* in_sizes, int n_in,
                              void* d_out, int out_size, void* d_ws, size_t ws_size,
                              hipStream_t stream)
{
    const float* x    = (const float*)d_in[0];
    const float* Wq   = (const float*)d_in[1];
    const float* bq   = (const float*)d_in[2];
    const float* Wk   = (const float*)d_in[3];
    const float* bk   = (const float*)d_in[4];
    const float* Wv   = (const float*)d_in[5];
    const float* bv   = (const float*)d_in[6];
    const float* ln_g = (const float*)d_in[7];
    const float* ln_b = (const float*)d_in[8];
    const float* W1   = (const float*)d_in[9];
    const float* b1   = (const float*)d_in[10];
    const float* W2   = (const float*)d_in[11];
    const float* b2   = (const float*)d_in[12];
    const float* lnffg = (const float*)d_in[13];
    const float* lnffb = (const float*)d_in[14];
    float* out = (float*)d_out;

    bf16* ws = (bf16*)d_ws;
    bf16* WT = ws;                        // 5 * 262144 bf16
    bf16* qb = ws + 5 * 262144;           // 8388608 bf16 each below
    bf16* kb = qb + 8388608;
    bf16* vT = kb + 8388608;
    bf16* vl = qb;                        // reuse (q dead after attention)
    bf16* f1 = kb;                        // reuse (k dead after attention)
    bf16* f2 = vT;                        // reuse (v dead after attention)
    bf16* xb = (bf16*)d_out;              // 16.7MB scratch; dead before attention writes O

    prep<<<9216, 256, 0, stream>>>(Wq, Wk, Wv, W1, W2, x, WT, xb);

    gemm_qk<<<dim3(128, 8), 256, 0, stream>>>(xb, WT, bq, bk, qb, kb);
    gemm_v <<<dim3(128, 8), 256, 0, stream>>>(xb, WT, bv, vT);

    attn_kernel<<<dim3(128, 16), 256, 0, stream>>>(qb, kb, vT, out);

    ln_kernel<true, true, false><<<4096, 256, 0, stream>>>(out, x, ln_g, ln_b, vl);

    dim3 gg(128, 8);
    gemm_bt<true> <<<gg, 256, 0, stream>>>(vl, WT + 3 * 262144, b1, f1);
    gemm_bt<false><<<gg, 256, 0, stream>>>(f1, WT + 4 * 262144, b2, f2);

    ln_kernel<false, false, true><<<4096, 256, 0, stream>>>(f2, nullptr, lnffg, lnffb, out);
}

// Round 13
// 244.284 us; speedup vs baseline: 1.0576x; 1.0555x over previous
//
#include <hip/hip_runtime.h>
#include <hip/hip_bf16.h>

using bf16 = __hip_bfloat16;
typedef unsigned int u32x4 __attribute__((ext_vector_type(4)));
typedef float f32x4 __attribute__((ext_vector_type(4)));
typedef __bf16 bf16x8 __attribute__((ext_vector_type(8)));

#define DEVI __device__ __forceinline__

DEVI f32x4 mfma16(u32x4 a, u32x4 b, f32x4 c) {
    return __builtin_amdgcn_mfma_f32_16x16x32_bf16(
        __builtin_bit_cast(bf16x8, a), __builtin_bit_cast(bf16x8, b), c, 0, 0, 0);
}

// async global->LDS DMA, 16B per lane; LDS dest = uniform base + lane*16
DEVI void gload16(const bf16* g, bf16* l) {
    __builtin_amdgcn_global_load_lds(
        (const __attribute__((address_space(1))) unsigned int*)g,
        (__attribute__((address_space(3))) unsigned int*)l,
        16, 0, 0);
}

struct bf8 { bf16 h[8]; };

DEVI u32x4 pack8(f32x4 lo, f32x4 hi) {
    bf8 t;
#pragma unroll
    for (int i = 0; i < 4; i++) {
        t.h[i] = __float2bfloat16(lo[i]);
        t.h[4 + i] = __float2bfloat16(hi[i]);
    }
    return __builtin_bit_cast(u32x4, t);
}

// RNE-packed 4x bf16 -> 64-bit
DEVI unsigned long long pk4(float a, float b, float c, float d) {
    union { unsigned long long u; bf16 h[4]; } t;
    t.h[0] = __float2bfloat16(a); t.h[1] = __float2bfloat16(b);
    t.h[2] = __float2bfloat16(c); t.h[3] = __float2bfloat16(d);
    return t.u;
}

// truncating bf16x2 pack (1 op)
DEVI unsigned trunc2(float a, float b) {
    return __builtin_amdgcn_perm(__builtin_bit_cast(unsigned, b),
                                 __builtin_bit_cast(unsigned, a), 0x07060302);
}

// ------------- prep: WT[n][k] = (bf16)W[k][n] (5 mats) + xb = (bf16)x --------
__global__ __launch_bounds__(256) void prep(
    const float* __restrict__ Wq, const float* __restrict__ Wk,
    const float* __restrict__ Wv, const float* __restrict__ W1,
    const float* __restrict__ W2, const float* __restrict__ x,
    bf16* __restrict__ WT, bf16* __restrict__ xb)
{
    int b = blockIdx.x;
    if (b < 5120) {
        int w = b >> 10;
        const float* src = (w == 0) ? Wq : (w == 1) ? Wk : (w == 2) ? Wv : (w == 3) ? W1 : W2;
        int idx = (b & 1023) * 256 + threadIdx.x;   // idx = n*512 + k
        int n = idx >> 9, kk = idx & 511;
        WT[(size_t)w * 262144 + idx] = __float2bfloat16(src[kk * 512 + n]);
    } else {
        size_t i = ((size_t)(b - 5120) * 256 + threadIdx.x) * 8;
        f32x4 lo = *(const f32x4*)&x[i];
        f32x4 hi = *(const f32x4*)&x[i + 4];
        *(u32x4*)&xb[i] = pack8(lo, hi);
    }
}

// ------------- GEMM cores: global_load_lds staging, XOR-swizzled LDS ---------
// LDS LINEAR (gload_lds writes lane-linear; padding forbidden). Conflict-free
// via XOR swizzle applied BOTH sides (rule 21):
//   write: per-lane global col = ((lane&7) ^ (lane>>3))*8
//   read : col ^= (lm&7)*8    (row&7 == lm&7 for every fragment row)
// DISCIPLINE (rounds 2-4,8,11,12 post-mortems):
//   * one body per kernel; no min-waves launch_bounds arg; no explicit LDS dbuf
//   * do NOT fuse LN into attn (r11) and do NOT shrink attn q-tiles (r12):
//     staging amortization per q-row is the binding quantity.
#define GEMM_BODY(EPILOGUE)                                                          \
    __shared__ __align__(16) bf16 As[128 * 64];                                      \
    __shared__ __align__(16) bf16 Bs[128 * 64];                                      \
    const int tid = threadIdx.x;                                                     \
    const int lane = tid & 63, wave = tid >> 6;                                      \
    const int wm = (wave >> 1) * 64, wn = (wave & 1) * 64;                           \
    const int lm = lane & 15, lq = lane >> 4;                                        \
    const int cxor = (lm & 7) * 8;                                                   \
    const int srow = wave * 32 + (lane >> 3);                                        \
    const int scol = ((lane & 7) ^ (lane >> 3)) * 8;                                 \
    const bf16* Ag = A + (size_t)(bm + srow) * 512 + scol;                           \
    const bf16* Bg = Bt + (size_t)(bn + srow) * 512 + scol;                          \
    bf16* Al = &As[wave * 32 * 64];                                                  \
    bf16* Bl = &Bs[wave * 32 * 64];                                                  \
    f32x4 acc[4][4];                                                                 \
    _Pragma("unroll") for (int i = 0; i < 4; i++)                                    \
        _Pragma("unroll") for (int j = 0; j < 4; j++)                                \
            acc[i][j] = (f32x4){0.f, 0.f, 0.f, 0.f};                                 \
    for (int k0 = 0; k0 < 512; k0 += 64) {                                           \
        __syncthreads();                                                             \
        _Pragma("unroll") for (int p = 0; p < 4; p++) {                              \
            gload16(Ag + (size_t)p * 8 * 512 + k0, Al + p * 512);                    \
            gload16(Bg + (size_t)p * 8 * 512 + k0, Bl + p * 512);                    \
        }                                                                            \
        __syncthreads();                                                             \
        _Pragma("unroll") for (int h = 0; h < 2; h++) {                              \
            u32x4 af[4], bfr[4];                                                     \
            _Pragma("unroll") for (int i = 0; i < 4; i++)                            \
                af[i] = *(const u32x4*)&As[(wm + i * 16 + lm) * 64 + ((h * 32 + lq * 8) ^ cxor)]; \
            _Pragma("unroll") for (int j = 0; j < 4; j++)                            \
                bfr[j] = *(const u32x4*)&Bs[(wn + j * 16 + lm) * 64 + ((h * 32 + lq * 8) ^ cxor)]; \
            EPILOGUE##_MMA                                                           \
        }                                                                            \
    }

#define SWAPPED_MMA                                                                  \
    _Pragma("unroll") for (int i = 0; i < 4; i++)                                    \
        _Pragma("unroll") for (int j = 0; j < 4; j++)                                \
            acc[i][j] = mfma16(bfr[j], af[i], acc[i][j]);

#define GEMM_BODY_N64(EPILOGUE)                                                      \
    __shared__ __align__(16) bf16 As[128 * 64];                                      \
    __shared__ __align__(16) bf16 Bs[64 * 64];                                       \
    const int tid = threadIdx.x;                                                     \
    const int lane = tid & 63, wave = tid >> 6;                                      \
    const int wm = wave * 32;                                                        \
    const int lm = lane & 15, lq = lane >> 4;                                        \
    const int cxor = (lm & 7) * 8;                                                   \
    const int sr8 = lane >> 3;                                                       \
    const int scol = ((lane & 7) ^ sr8) * 8;                                         \
    const bf16* Ag = A + (size_t)(bm + wave * 32 + sr8) * 512 + scol;                \
    const bf16* Bg = Bt + (size_t)(bn + wave * 16 + sr8) * 512 + scol;               \
    bf16* Al = &As[wave * 32 * 64];                                                  \
    bf16* Bl = &Bs[wave * 16 * 64];                                                  \
    f32x4 acc[2][4];                                                                 \
    _Pragma("unroll") for (int i = 0; i < 2; i++)                                    \
        _Pragma("unroll") for (int j = 0; j < 4; j++)                                \
            acc[i][j] = (f32x4){0.f, 0.f, 0.f, 0.f};                                 \
    for (int k0 = 0; k0 < 512; k0 += 64) {                                           \
        __syncthreads();                                                             \
        _Pragma("unroll") for (int p = 0; p < 4; p++)                                \
            gload16(Ag + (size_t)p * 8 * 512 + k0, Al + p * 512);                    \
        _Pragma("unroll") for (int p = 0; p < 2; p++)                                \
            gload16(Bg + (size_t)p * 8 * 512 + k0, Bl + p * 512);                    \
        __syncthreads();                                                             \
        _Pragma("unroll") for (int h = 0; h < 2; h++) {                              \
            u32x4 af[2], bfr[4];                                                     \
            _Pragma("unroll") for (int i = 0; i < 2; i++)                            \
                af[i] = *(const u32x4*)&As[(wm + i * 16 + lm) * 64 + ((h * 32 + lq * 8) ^ cxor)]; \
            _Pragma("unroll") for (int j = 0; j < 4; j++)                            \
                bfr[j] = *(const u32x4*)&Bs[(j * 16 + lm) * 64 + ((h * 32 + lq * 8) ^ cxor)]; \
            EPILOGUE##_MMA_N64                                                       \
        }                                                                            \
    }

#define SWAPPED_MMA_N64                                                              \
    _Pragma("unroll") for (int i = 0; i < 2; i++)                                    \
        _Pragma("unroll") for (int j = 0; j < 4; j++)                                \
            acc[i][j] = mfma16(bfr[j], af[i], acc[i][j]);
#define NORMAL_MMA_N64                                                               \
    _Pragma("unroll") for (int i = 0; i < 2; i++)                                    \
        _Pragma("unroll") for (int j = 0; j < 4; j++)                                \
            acc[i][j] = mfma16(af[i], bfr[j], acc[i][j]);

// ------------- Q/K GEMM (swapped orientation), 128x128, 4 blk/CU -------------
__global__ __launch_bounds__(256) void gemm_qk(
    const bf16* __restrict__ A, const bf16* __restrict__ WT,
    const float* __restrict__ bqp, const float* __restrict__ bkp,
    bf16* __restrict__ qb, bf16* __restrict__ kb)
{
    const int wsel = blockIdx.y >> 2;                  // 0=q 1=k
    const int bm = blockIdx.x * 128, bn = (blockIdx.y & 3) * 128;
    const bf16* Bt = WT + (size_t)wsel * 262144;
    const float* bias = (wsel == 0) ? bqp : bkp;
    const float scale = (wsel == 0) ? 0.18033688f : 1.0f;   // log2e/8 into q
    bf16* dst = (wsel == 0) ? qb : kb;

    GEMM_BODY(SWAPPED)
#pragma unroll
    for (int i = 0; i < 4; i++) {
#pragma unroll
        for (int j = 0; j < 4; j++) {
            int row = bm + wm + i * 16 + lm;
            int colb = bn + wn + j * 16 + lq * 4;
            f32x4 b4 = *(const f32x4*)&bias[colb];
            *(unsigned long long*)&dst[(size_t)row * 512 + colb] =
                pk4((acc[i][j][0] + b4[0]) * scale, (acc[i][j][1] + b4[1]) * scale,
                    (acc[i][j][2] + b4[2]) * scale, (acc[i][j][3] + b4[3]) * scale);
        }
    }
}

// ------------- V GEMM (normal orientation) -> vT pack, 128x64 tile -----------
// vT key permutation (consumed by attn PV as the MFMA k-slot order):
//   within each 32-key block, key u = 16h + 4a + t  (h:1b, a:2b, t:2b)
//   is stored at column cc = 8a + 4h + t.
__global__ __launch_bounds__(256) void gemm_v(
    const bf16* __restrict__ A, const bf16* __restrict__ WT,
    const float* __restrict__ bvp, bf16* __restrict__ vT)
{
    const int bm = blockIdx.x * 128, bn = blockIdx.y * 64;
    const bf16* Bt = WT + (size_t)2 * 262144;
    const float* bias = bvp;

    GEMM_BODY_N64(NORMAL)
#pragma unroll
    for (int i = 0; i < 2; i++) {
#pragma unroll
        for (int j = 0; j < 4; j++) {
            int col = bn + j * 16 + lm;
            float bv = bias[col];
            int rowb = bm + wm + i * 16 + lq * 4;   // 4 consecutive nodes (mult of 4)
            int btq = rowb >> 10, node = rowb & 1023;
            int u = node & 31;                      // u&3 == 0 always
            int nodeP = (node & ~31) | (((u >> 2) & 3) << 3) | (((u >> 4) & 1) << 2);
            *(unsigned long long*)&vT[((size_t)((btq * 8 + (col >> 6)) * 64 + (col & 63))) * 1024 + nodeP] =
                pk4(acc[i][j][0] + bv, acc[i][j][1] + bv,
                    acc[i][j][2] + bv, acc[i][j][3] + bv);
        }
    }
}

// ------------- FFN GEMM (RELU or plain), swapped, 128x64 tile ----------------
template <bool RELU>
__global__ __launch_bounds__(256) void gemm_bt(
    const bf16* __restrict__ A, const bf16* __restrict__ Bt,
    const float* __restrict__ bias, bf16* __restrict__ C)
{
    const int bm = blockIdx.x * 128, bn = blockIdx.y * 64;
    GEMM_BODY_N64(SWAPPED)
#pragma unroll
    for (int i = 0; i < 2; i++) {
#pragma unroll
        for (int j = 0; j < 4; j++) {
            int row = bm + wm + i * 16 + lm;
            int colb = bn + j * 16 + lq * 4;
            f32x4 b4 = *(const f32x4*)&bias[colb];
            float c0 = acc[i][j][0] + b4[0], c1 = acc[i][j][1] + b4[1];
            float c2 = acc[i][j][2] + b4[2], c3 = acc[i][j][3] + b4[3];
            if (RELU) {
                c0 = fmaxf(c0, 0.f); c1 = fmaxf(c1, 0.f);
                c2 = fmaxf(c2, 0.f); c3 = fmaxf(c3, 0.f);
            }
            *(unsigned long long*)&C[(size_t)row * 512 + colb] = pk4(c0, c1, c2, c3);
        }
    }
}

// ------------- flash attention: register-P, O^T = V^T * P^T ------------------
// Round-9 proven config (44.8 us): 128-row q-tiles, double-buffered K/V LDS
// (36,864 B), ONE barrier per K-tile, register prefetch across compute.
// ONLY change vs round 9: o is stored as bf16 (halves write; o| <~0.15 so
// bf16 rounding ~3e-4 abs, negligible vs absmax 0.03125).
// q (pre-scaled by log2e/8), k: [16384 x 512] bf16
// vT: [(g)*64+d][1024] bf16, keys PERMUTED within 32-blocks (see gemm_v).
// o: [16384 x 512] bf16.  grid(128 groups, 8 qtiles of 128 rows), 256 thr.
__global__ __launch_bounds__(256, 4) void attn_kernel(
    const bf16* __restrict__ q, const bf16* __restrict__ k,
    const bf16* __restrict__ vT, bf16* __restrict__ o)
{
    constexpr int KP = 72;   // 144 B stride: 16-B aligned, free 2-way
    constexpr int VP = 72;
    __shared__ __align__(16) bf16 Ks[2][64 * KP];     // [buf][key][d]
    __shared__ __align__(16) bf16 Vs[2][64 * VP];     // [buf][d][perm-key]

    const int tid = threadIdx.x, lane = tid & 63, wave = tid >> 6;
    const int group = blockIdx.x;          // bt*8 + h
    const int bt = group >> 3, hh = group & 7;
    const int lm = lane & 15, lq = lane >> 4;
    const int qrow0 = bt * 1024 + blockIdx.y * 128 + wave * 32;

    u32x4 qf[2][2];
#pragma unroll
    for (int tm = 0; tm < 2; tm++)
#pragma unroll
        for (int kk2 = 0; kk2 < 2; kk2++)
            qf[tm][kk2] = *(const u32x4*)&q[(size_t)(qrow0 + tm * 16 + lm) * 512 + hh * 64 + kk2 * 32 + lq * 8];

    const bf16* kbase = k + (size_t)(bt * 1024) * 512 + hh * 64;   // + row*512 + e
    const bf16* vbase = vT + (size_t)group * 64 * 1024;            // + d*1024 + key

    // staging coords (per thread, 2 chunks of 64-el rows)
    const int r0 = tid >> 3, e0 = (tid & 7) * 8;
    const int r1 = (256 + tid) >> 3;

    // ones A-fragment: A[row 0][k]=1.0 for all k, other rows 0
    const unsigned ow = (lm == 0) ? 0x3F803F80u : 0u;
    const u32x4 onesA = (u32x4){ow, ow, ow, ow};

    f32x4 accO[4][2];   // [d-tile][q-tile], O^T orientation
#pragma unroll
    for (int md = 0; md < 4; md++)
#pragma unroll
        for (int tm = 0; tm < 2; tm++) accO[md][tm] = (f32x4){0.f, 0.f, 0.f, 0.f};
    f32x4 accL[2] = {(f32x4){0.f, 0.f, 0.f, 0.f}, (f32x4){0.f, 0.f, 0.f, 0.f}};

    // prefetch kt=0
    u32x4 kreg0 = *(const u32x4*)&kbase[(size_t)r0 * 512 + e0];
    u32x4 kreg1 = *(const u32x4*)&kbase[(size_t)r1 * 512 + e0];
    u32x4 vreg0 = *(const u32x4*)&vbase[(size_t)r0 * 1024 + e0];
    u32x4 vreg1 = *(const u32x4*)&vbase[(size_t)r1 * 1024 + e0];

    for (int kt = 0; kt < 16; kt++) {
        bf16* Kb = Ks[kt & 1];
        bf16* Vb = Vs[kt & 1];
        *(u32x4*)&Kb[r0 * KP + e0] = kreg0;
        *(u32x4*)&Kb[r1 * KP + e0] = kreg1;
        *(u32x4*)&Vb[r0 * VP + e0] = vreg0;
        *(u32x4*)&Vb[r1 * VP + e0] = vreg1;
        __syncthreads();   // single barrier per K-tile (double-buffered)
        if (kt < 15) {     // prefetch: in flight across whole compute phase
            const bf16* kn = kbase + (size_t)((kt + 1) * 64) * 512;
            const bf16* vn = vbase + (kt + 1) * 64;
            kreg0 = *(const u32x4*)&kn[(size_t)r0 * 512 + e0];
            kreg1 = *(const u32x4*)&kn[(size_t)r1 * 512 + e0];
            vreg0 = *(const u32x4*)&vn[(size_t)r0 * 1024 + e0];
            vreg1 = *(const u32x4*)&vn[(size_t)r1 * 1024 + e0];
        }

#pragma unroll
        for (int kc = 0; kc < 2; kc++) {
            const int t0 = kc * 2;
            // S^T tiles for this 32-key contraction: A=K (m=key), B=Q (n=q)
            u32x4 kf00 = *(const u32x4*)&Kb[(t0 * 16 + lm) * KP + lq * 8];
            u32x4 kf01 = *(const u32x4*)&Kb[(t0 * 16 + lm) * KP + 32 + lq * 8];
            u32x4 kf10 = *(const u32x4*)&Kb[((t0 + 1) * 16 + lm) * KP + lq * 8];
            u32x4 kf11 = *(const u32x4*)&Kb[((t0 + 1) * 16 + lm) * KP + 32 + lq * 8];
            u32x4 pw[2];
#pragma unroll
            for (int tm = 0; tm < 2; tm++) {
                f32x4 s0 = (f32x4){0.f, 0.f, 0.f, 0.f};
                s0 = mfma16(kf00, qf[tm][0], s0);
                s0 = mfma16(kf01, qf[tm][1], s0);
                f32x4 s1 = (f32x4){0.f, 0.f, 0.f, 0.f};
                s1 = mfma16(kf10, qf[tm][0], s1);
                s1 = mfma16(kf11, qf[tm][1], s1);
                float p0 = __builtin_amdgcn_exp2f(s0[0]);
                float p1 = __builtin_amdgcn_exp2f(s0[1]);
                float p2 = __builtin_amdgcn_exp2f(s0[2]);
                float p3 = __builtin_amdgcn_exp2f(s0[3]);
                float p4 = __builtin_amdgcn_exp2f(s1[0]);
                float p5 = __builtin_amdgcn_exp2f(s1[1]);
                float p6 = __builtin_amdgcn_exp2f(s1[2]);
                float p7 = __builtin_amdgcn_exp2f(s1[3]);
                // slots 0-3 = tile t0 keys lq*4+r ; slots 4-7 = tile t0+1
                pw[tm] = (u32x4){trunc2(p0, p1), trunc2(p2, p3),
                                 trunc2(p4, p5), trunc2(p6, p7)};
            }
            // denominator: l += sum_k P (ones-row MFMA, off the VALU)
            accL[0] = mfma16(onesA, pw[0], accL[0]);
            accL[1] = mfma16(onesA, pw[1], accL[1]);
            // O^T += V^T * P^T : A = V^T from Vs (perm keys match pw slots)
            __builtin_amdgcn_s_setprio(1);
#pragma unroll
            for (int md = 0; md < 4; md++) {
                u32x4 vf = *(const u32x4*)&Vb[(md * 16 + lm) * VP + kc * 32 + lq * 8];
                accO[md][0] = mfma16(vf, pw[0], accO[md][0]);
                accO[md][1] = mfma16(vf, pw[1], accO[md][1]);
            }
            __builtin_amdgcn_s_setprio(0);
        }
    }

    // l lives in reg0 of lanes lq==0; xor-reduce over lq broadcasts to all.
#pragma unroll
    for (int tm = 0; tm < 2; tm++) {
        float l = accL[tm][0];
        l += __shfl_xor(l, 16);
        l += __shfl_xor(l, 32);
        float linv = 1.0f / l;
#pragma unroll
        for (int md = 0; md < 4; md++) {
            // row = q (lm), cols = hh*64 + md*16 + lq*4 .. +3 (8B bf16 store)
            *(unsigned long long*)&o[(size_t)(qrow0 + tm * 16 + lm) * 512 + hh * 64 + md * 16 + lq * 4] =
                pk4(accO[md][tm][0] * linv, accO[md][tm][1] * linv,
                    accO[md][tm][2] * linv, accO[md][tm][3] * linv);
        }
    }
}

// ------------- LayerNorm (one wave per 512-el row) ---------------------------
template <bool AF32, bool RES, bool OF32>
__global__ __launch_bounds__(256) void ln_kernel(
    const void* __restrict__ a, const float* __restrict__ res,
    const float* __restrict__ g, const float* __restrict__ bb, void* __restrict__ out)
{
    int row = blockIdx.x * 4 + (threadIdx.x >> 6);
    int lane = threadIdx.x & 63;
    size_t base = (size_t)row * 512 + lane * 8;
    int cbase = lane * 8;

    float x8[8];
    if (AF32) {
        const float* af = (const float*)a;
        f32x4 lo = *(const f32x4*)&af[base];
        f32x4 hi = *(const f32x4*)&af[base + 4];
#pragma unroll
        for (int i = 0; i < 4; i++) { x8[i] = lo[i]; x8[4 + i] = hi[i]; }
    } else {
        bf8 av = __builtin_bit_cast(bf8, *(const u32x4*)&((const bf16*)a)[base]);
#pragma unroll
        for (int i = 0; i < 8; i++) x8[i] = __bfloat162float(av.h[i]);
    }
    if (RES) {
        f32x4 lo = *(const f32x4*)&res[base];
        f32x4 hi = *(const f32x4*)&res[base + 4];
#pragma unroll
        for (int i = 0; i < 4; i++) { x8[i] += lo[i]; x8[4 + i] += hi[i]; }
    }

    float s = 0.f, s2 = 0.f;
#pragma unroll
    for (int i = 0; i < 8; i++) { s += x8[i]; s2 += x8[i] * x8[i]; }
#pragma unroll
    for (int off = 1; off < 64; off <<= 1) {
        s += __shfl_xor(s, off);
        s2 += __shfl_xor(s2, off);
    }
    float mean = s * (1.f / 512.f);
    float var = s2 * (1.f / 512.f) - mean * mean;
    float rstd = rsqrtf(var + 1e-5f);

    f32x4 g0 = *(const f32x4*)&g[cbase], g1 = *(const f32x4*)&g[cbase + 4];
    f32x4 b0 = *(const f32x4*)&bb[cbase], b1v = *(const f32x4*)&bb[cbase + 4];
    float y[8];
#pragma unroll
    for (int i = 0; i < 4; i++) {
        y[i] = (x8[i] - mean) * rstd * g0[i] + b0[i];
        y[4 + i] = (x8[4 + i] - mean) * rstd * g1[i] + b1v[i];
    }
    if (OF32) {
        float* op = (float*)out;
        *(f32x4*)&op[base] = (f32x4){y[0], y[1], y[2], y[3]};
        *(f32x4*)&op[base + 4] = (f32x4){y[4], y[5], y[6], y[7]};
    } else {
        bf8 ov;
#pragma unroll
        for (int i = 0; i < 8; i++) ov.h[i] = __float2bfloat16(y[i]);
        *(u32x4*)&((bf16*)out)[base] = __builtin_bit_cast(u32x4, ov);
    }
}

// ------------- launch --------------------------------------------------------
extern "C" void kernel_launch(void* const* d_in, const int* in_sizes, int n_in,
                              void* d_out, int out_size, void* d_ws, size_t ws_size,
                              hipStream_t stream)
{
    const float* x    = (const float*)d_in[0];
    const float* Wq   = (const float*)d_in[1];
    const float* bq   = (const float*)d_in[2];
    const float* Wk   = (const float*)d_in[3];
    const float* bk   = (const float*)d_in[4];
    const float* Wv   = (const float*)d_in[5];
    const float* bv   = (const float*)d_in[6];
    const float* ln_g = (const float*)d_in[7];
    const float* ln_b = (const float*)d_in[8];
    const float* W1   = (const float*)d_in[9];
    const float* b1   = (const float*)d_in[10];
    const float* W2   = (const float*)d_in[11];
    const float* b2   = (const float*)d_in[12];
    const float* lnffg = (const float*)d_in[13];
    const float* lnffb = (const float*)d_in[14];
    float* out = (float*)d_out;

    bf16* ws = (bf16*)d_ws;
    bf16* WT = ws;                        // 5 * 262144 bf16
    bf16* qb = ws + 5 * 262144;           // 8388608 bf16 each below
    bf16* kb = qb + 8388608;
    bf16* vT = kb + 8388608;
    bf16* vl = qb;                        // reuse (q dead after attention)
    bf16* f1 = kb;                        // reuse (k dead after attention)
    bf16* f2 = vT;                        // reuse (v dead after attention)
    // d_out (33,554,432 B) split: first half xb (8.4M bf16), second half ob.
    // xb dead after gemm_qk/gemm_v; ob dead after ln#1; final ln overwrites all.
    bf16* xb = (bf16*)d_out;
    bf16* ob = xb + 8388608;

    prep<<<9216, 256, 0, stream>>>(Wq, Wk, Wv, W1, W2, x, WT, xb);

    gemm_qk<<<dim3(128, 8), 256, 0, stream>>>(xb, WT, bq, bk, qb, kb);
    gemm_v <<<dim3(128, 8), 256, 0, stream>>>(xb, WT, bv, vT);

    attn_kernel<<<dim3(128, 8), 256, 0, stream>>>(qb, kb, vT, ob);

    ln_kernel<false, true, false><<<4096, 256, 0, stream>>>(ob, x, ln_g, ln_b, vl);

    dim3 gg(128, 8);
    gemm_bt<true> <<<gg, 256, 0, stream>>>(vl, WT + 3 * 262144, b1, f1);
    gemm_bt<false><<<gg, 256, 0, stream>>>(f1, WT + 4 * 262144, b2, f2);

    ln_kernel<false, false, true><<<4096, 256, 0, stream>>>(f2, nullptr, lnffg, lnffb, out);
}

// Round 14
// 239.699 us; speedup vs baseline: 1.0778x; 1.0191x over previous
//
#include <hip/hip_runtime.h>
#include <hip/hip_bf16.h>

using bf16 = __hip_bfloat16;
typedef unsigned int u32x4 __attribute__((ext_vector_type(4)));
typedef float f32x4 __attribute__((ext_vector_type(4)));
typedef __bf16 bf16x8 __attribute__((ext_vector_type(8)));

#define DEVI __device__ __forceinline__

DEVI f32x4 mfma16(u32x4 a, u32x4 b, f32x4 c) {
    return __builtin_amdgcn_mfma_f32_16x16x32_bf16(
        __builtin_bit_cast(bf16x8, a), __builtin_bit_cast(bf16x8, b), c, 0, 0, 0);
}

// async global->LDS DMA, 16B per lane; LDS dest = uniform base + lane*16
DEVI void gload16(const bf16* g, bf16* l) {
    __builtin_amdgcn_global_load_lds(
        (const __attribute__((address_space(1))) unsigned int*)g,
        (__attribute__((address_space(3))) unsigned int*)l,
        16, 0, 0);
}

struct bf8 { bf16 h[8]; };

DEVI u32x4 pack8(f32x4 lo, f32x4 hi) {
    bf8 t;
#pragma unroll
    for (int i = 0; i < 4; i++) {
        t.h[i] = __float2bfloat16(lo[i]);
        t.h[4 + i] = __float2bfloat16(hi[i]);
    }
    return __builtin_bit_cast(u32x4, t);
}

// RNE-packed 4x bf16 -> 64-bit
DEVI unsigned long long pk4(float a, float b, float c, float d) {
    union { unsigned long long u; bf16 h[4]; } t;
    t.h[0] = __float2bfloat16(a); t.h[1] = __float2bfloat16(b);
    t.h[2] = __float2bfloat16(c); t.h[3] = __float2bfloat16(d);
    return t.u;
}

// truncating bf16x2 pack (1 op)
DEVI unsigned trunc2(float a, float b) {
    return __builtin_amdgcn_perm(__builtin_bit_cast(unsigned, b),
                                 __builtin_bit_cast(unsigned, a), 0x07060302);
}

// ------------- prep: WT[n][k] = (bf16)W[k][n] via LDS-tiled transpose --------
// Round-13 fix: the old per-element transpose read W with 2KB stride (64B line
// per 4 useful bytes, ~16x over-fetch). Now: 64x64 f32 tiles through LDS
// T[64][65] — both the global read and the transposed write are 256B/wave
// coalesced; pad-65 makes the transposed LDS read conflict-free.
// Blocks 0..319: 5 matrices x 64 tiles. Blocks 320+: xb = (bf16)x.
__global__ __launch_bounds__(256) void prep(
    const float* __restrict__ Wq, const float* __restrict__ Wk,
    const float* __restrict__ Wv, const float* __restrict__ W1,
    const float* __restrict__ W2, const float* __restrict__ x,
    bf16* __restrict__ WT, bf16* __restrict__ xb)
{
    __shared__ float T[64][65];
    int b = blockIdx.x;
    if (b < 320) {
        int w = b >> 6;                 // matrix 0..4
        int t = b & 63;                 // tile 0..63
        int kk0 = (t >> 3) * 64, n0 = (t & 7) * 64;
        const float* src = (w == 0) ? Wq : (w == 1) ? Wk : (w == 2) ? Wv : (w == 3) ? W1 : W2;
        const int r4 = threadIdx.x >> 6;    // wave id 0..3 (row offset)
        const int c = threadIdx.x & 63;     // lane
#pragma unroll
        for (int p = 0; p < 16; p++) {
            int row = p * 4 + r4;
            T[row][c] = src[(size_t)(kk0 + row) * 512 + n0 + c];
        }
        __syncthreads();
#pragma unroll
        for (int p = 0; p < 16; p++) {
            int nrow = p * 4 + r4;
            WT[(size_t)w * 262144 + (size_t)(n0 + nrow) * 512 + kk0 + c] =
                __float2bfloat16(T[c][nrow]);
        }
    } else {
        size_t i = ((size_t)(b - 320) * 256 + threadIdx.x) * 8;
        f32x4 lo = *(const f32x4*)&x[i];
        f32x4 hi = *(const f32x4*)&x[i + 4];
        *(u32x4*)&xb[i] = pack8(lo, hi);
    }
}

// ------------- GEMM cores: global_load_lds staging, XOR-swizzled LDS ---------
// LDS LINEAR (gload_lds writes lane-linear; padding forbidden). Conflict-free
// via XOR swizzle applied BOTH sides (rule 21):
//   write: per-lane global col = ((lane&7) ^ (lane>>3))*8
//   read : col ^= (lm&7)*8    (row&7 == lm&7 for every fragment row)
// DISCIPLINE (rounds 2-4,8,11,12 post-mortems):
//   * one body per kernel; no min-waves launch_bounds arg; no explicit LDS dbuf
//   * do NOT fuse LN into attn (r11) and do NOT shrink attn q-tiles (r12):
//     staging amortization per q-row is the binding quantity.
#define GEMM_BODY(EPILOGUE)                                                          \
    __shared__ __align__(16) bf16 As[128 * 64];                                      \
    __shared__ __align__(16) bf16 Bs[128 * 64];                                      \
    const int tid = threadIdx.x;                                                     \
    const int lane = tid & 63, wave = tid >> 6;                                      \
    const int wm = (wave >> 1) * 64, wn = (wave & 1) * 64;                           \
    const int lm = lane & 15, lq = lane >> 4;                                        \
    const int cxor = (lm & 7) * 8;                                                   \
    const int srow = wave * 32 + (lane >> 3);                                        \
    const int scol = ((lane & 7) ^ (lane >> 3)) * 8;                                 \
    const bf16* Ag = A + (size_t)(bm + srow) * 512 + scol;                           \
    const bf16* Bg = Bt + (size_t)(bn + srow) * 512 + scol;                          \
    bf16* Al = &As[wave * 32 * 64];                                                  \
    bf16* Bl = &Bs[wave * 32 * 64];                                                  \
    f32x4 acc[4][4];                                                                 \
    _Pragma("unroll") for (int i = 0; i < 4; i++)                                    \
        _Pragma("unroll") for (int j = 0; j < 4; j++)                                \
            acc[i][j] = (f32x4){0.f, 0.f, 0.f, 0.f};                                 \
    for (int k0 = 0; k0 < 512; k0 += 64) {                                           \
        __syncthreads();                                                             \
        _Pragma("unroll") for (int p = 0; p < 4; p++) {                              \
            gload16(Ag + (size_t)p * 8 * 512 + k0, Al + p * 512);                    \
            gload16(Bg + (size_t)p * 8 * 512 + k0, Bl + p * 512);                    \
        }                                                                            \
        __syncthreads();                                                             \
        _Pragma("unroll") for (int h = 0; h < 2; h++) {                              \
            u32x4 af[4], bfr[4];                                                     \
            _Pragma("unroll") for (int i = 0; i < 4; i++)                            \
                af[i] = *(const u32x4*)&As[(wm + i * 16 + lm) * 64 + ((h * 32 + lq * 8) ^ cxor)]; \
            _Pragma("unroll") for (int j = 0; j < 4; j++)                            \
                bfr[j] = *(const u32x4*)&Bs[(wn + j * 16 + lm) * 64 + ((h * 32 + lq * 8) ^ cxor)]; \
            EPILOGUE##_MMA                                                           \
        }                                                                            \
    }

#define SWAPPED_MMA                                                                  \
    _Pragma("unroll") for (int i = 0; i < 4; i++)                                    \
        _Pragma("unroll") for (int j = 0; j < 4; j++)                                \
            acc[i][j] = mfma16(bfr[j], af[i], acc[i][j]);

#define GEMM_BODY_N64(EPILOGUE)                                                      \
    __shared__ __align__(16) bf16 As[128 * 64];                                      \
    __shared__ __align__(16) bf16 Bs[64 * 64];                                       \
    const int tid = threadIdx.x;                                                     \
    const int lane = tid & 63, wave = tid >> 6;                                      \
    const int wm = wave * 32;                                                        \
    const int lm = lane & 15, lq = lane >> 4;                                        \
    const int cxor = (lm & 7) * 8;                                                   \
    const int sr8 = lane >> 3;                                                       \
    const int scol = ((lane & 7) ^ sr8) * 8;                                         \
    const bf16* Ag = A + (size_t)(bm + wave * 32 + sr8) * 512 + scol;                \
    const bf16* Bg = Bt + (size_t)(bn + wave * 16 + sr8) * 512 + scol;               \
    bf16* Al = &As[wave * 32 * 64];                                                  \
    bf16* Bl = &Bs[wave * 16 * 64];                                                  \
    f32x4 acc[2][4];                                                                 \
    _Pragma("unroll") for (int i = 0; i < 2; i++)                                    \
        _Pragma("unroll") for (int j = 0; j < 4; j++)                                \
            acc[i][j] = (f32x4){0.f, 0.f, 0.f, 0.f};                                 \
    for (int k0 = 0; k0 < 512; k0 += 64) {                                           \
        __syncthreads();                                                             \
        _Pragma("unroll") for (int p = 0; p < 4; p++)                                \
            gload16(Ag + (size_t)p * 8 * 512 + k0, Al + p * 512);                    \
        _Pragma("unroll") for (int p = 0; p < 2; p++)                                \
            gload16(Bg + (size_t)p * 8 * 512 + k0, Bl + p * 512);                    \
        __syncthreads();                                                             \
        _Pragma("unroll") for (int h = 0; h < 2; h++) {                              \
            u32x4 af[2], bfr[4];                                                     \
            _Pragma("unroll") for (int i = 0; i < 2; i++)                            \
                af[i] = *(const u32x4*)&As[(wm + i * 16 + lm) * 64 + ((h * 32 + lq * 8) ^ cxor)]; \
            _Pragma("unroll") for (int j = 0; j < 4; j++)                            \
                bfr[j] = *(const u32x4*)&Bs[(j * 16 + lm) * 64 + ((h * 32 + lq * 8) ^ cxor)]; \
            EPILOGUE##_MMA_N64                                                       \
        }                                                                            \
    }

#define SWAPPED_MMA_N64                                                              \
    _Pragma("unroll") for (int i = 0; i < 2; i++)                                    \
        _Pragma("unroll") for (int j = 0; j < 4; j++)                                \
            acc[i][j] = mfma16(bfr[j], af[i], acc[i][j]);
#define NORMAL_MMA_N64                                                               \
    _Pragma("unroll") for (int i = 0; i < 2; i++)                                    \
        _Pragma("unroll") for (int j = 0; j < 4; j++)                                \
            acc[i][j] = mfma16(af[i], bfr[j], acc[i][j]);

// ------------- Q/K GEMM (swapped orientation), 128x128, 4 blk/CU -------------
__global__ __launch_bounds__(256) void gemm_qk(
    const bf16* __restrict__ A, const bf16* __restrict__ WT,
    const float* __restrict__ bqp, const float* __restrict__ bkp,
    bf16* __restrict__ qb, bf16* __restrict__ kb)
{
    const int wsel = blockIdx.y >> 2;                  // 0=q 1=k
    const int bm = blockIdx.x * 128, bn = (blockIdx.y & 3) * 128;
    const bf16* Bt = WT + (size_t)wsel * 262144;
    const float* bias = (wsel == 0) ? bqp : bkp;
    const float scale = (wsel == 0) ? 0.18033688f : 1.0f;   // log2e/8 into q
    bf16* dst = (wsel == 0) ? qb : kb;

    GEMM_BODY(SWAPPED)
#pragma unroll
    for (int i = 0; i < 4; i++) {
#pragma unroll
        for (int j = 0; j < 4; j++) {
            int row = bm + wm + i * 16 + lm;
            int colb = bn + wn + j * 16 + lq * 4;
            f32x4 b4 = *(const f32x4*)&bias[colb];
            *(unsigned long long*)&dst[(size_t)row * 512 + colb] =
                pk4((acc[i][j][0] + b4[0]) * scale, (acc[i][j][1] + b4[1]) * scale,
                    (acc[i][j][2] + b4[2]) * scale, (acc[i][j][3] + b4[3]) * scale);
        }
    }
}

// ------------- V GEMM (normal orientation) -> vT pack, 128x64 tile -----------
// vT key permutation (consumed by attn PV as the MFMA k-slot order):
//   within each 32-key block, key u = 16h + 4a + t  (h:1b, a:2b, t:2b)
//   is stored at column cc = 8a + 4h + t.
__global__ __launch_bounds__(256) void gemm_v(
    const bf16* __restrict__ A, const bf16* __restrict__ WT,
    const float* __restrict__ bvp, bf16* __restrict__ vT)
{
    const int bm = blockIdx.x * 128, bn = blockIdx.y * 64;
    const bf16* Bt = WT + (size_t)2 * 262144;
    const float* bias = bvp;

    GEMM_BODY_N64(NORMAL)
#pragma unroll
    for (int i = 0; i < 2; i++) {
#pragma unroll
        for (int j = 0; j < 4; j++) {
            int col = bn + j * 16 + lm;
            float bv = bias[col];
            int rowb = bm + wm + i * 16 + lq * 4;   // 4 consecutive nodes (mult of 4)
            int btq = rowb >> 10, node = rowb & 1023;
            int u = node & 31;                      // u&3 == 0 always
            int nodeP = (node & ~31) | (((u >> 2) & 3) << 3) | (((u >> 4) & 1) << 2);
            *(unsigned long long*)&vT[((size_t)((btq * 8 + (col >> 6)) * 64 + (col & 63))) * 1024 + nodeP] =
                pk4(acc[i][j][0] + bv, acc[i][j][1] + bv,
                    acc[i][j][2] + bv, acc[i][j][3] + bv);
        }
    }
}

// ------------- FFN GEMM (RELU or plain), swapped, 128x64 tile ----------------
template <bool RELU>
__global__ __launch_bounds__(256) void gemm_bt(
    const bf16* __restrict__ A, const bf16* __restrict__ Bt,
    const float* __restrict__ bias, bf16* __restrict__ C)
{
    const int bm = blockIdx.x * 128, bn = blockIdx.y * 64;
    GEMM_BODY_N64(SWAPPED)
#pragma unroll
    for (int i = 0; i < 2; i++) {
#pragma unroll
        for (int j = 0; j < 4; j++) {
            int row = bm + wm + i * 16 + lm;
            int colb = bn + j * 16 + lq * 4;
            f32x4 b4 = *(const f32x4*)&bias[colb];
            float c0 = acc[i][j][0] + b4[0], c1 = acc[i][j][1] + b4[1];
            float c2 = acc[i][j][2] + b4[2], c3 = acc[i][j][3] + b4[3];
            if (RELU) {
                c0 = fmaxf(c0, 0.f); c1 = fmaxf(c1, 0.f);
                c2 = fmaxf(c2, 0.f); c3 = fmaxf(c3, 0.f);
            }
            *(unsigned long long*)&C[(size_t)row * 512 + colb] = pk4(c0, c1, c2, c3);
        }
    }
}

// ------------- flash attention: register-P, O^T = V^T * P^T ------------------
// Round-9 proven config: 128-row q-tiles, double-buffered K/V LDS (36,864 B),
// ONE barrier per K-tile, register prefetch across compute; o stored bf16.
// q (pre-scaled by log2e/8), k: [16384 x 512] bf16
// vT: [(g)*64+d][1024] bf16, keys PERMUTED within 32-blocks (see gemm_v).
// o: [16384 x 512] bf16.  grid(128 groups, 8 qtiles of 128 rows), 256 thr.
__global__ __launch_bounds__(256, 4) void attn_kernel(
    const bf16* __restrict__ q, const bf16* __restrict__ k,
    const bf16* __restrict__ vT, bf16* __restrict__ o)
{
    constexpr int KP = 72;   // 144 B stride: 16-B aligned, free 2-way
    constexpr int VP = 72;
    __shared__ __align__(16) bf16 Ks[2][64 * KP];     // [buf][key][d]
    __shared__ __align__(16) bf16 Vs[2][64 * VP];     // [buf][d][perm-key]

    const int tid = threadIdx.x, lane = tid & 63, wave = tid >> 6;
    const int group = blockIdx.x;          // bt*8 + h
    const int bt = group >> 3, hh = group & 7;
    const int lm = lane & 15, lq = lane >> 4;
    const int qrow0 = bt * 1024 + blockIdx.y * 128 + wave * 32;

    u32x4 qf[2][2];
#pragma unroll
    for (int tm = 0; tm < 2; tm++)
#pragma unroll
        for (int kk2 = 0; kk2 < 2; kk2++)
            qf[tm][kk2] = *(const u32x4*)&q[(size_t)(qrow0 + tm * 16 + lm) * 512 + hh * 64 + kk2 * 32 + lq * 8];

    const bf16* kbase = k + (size_t)(bt * 1024) * 512 + hh * 64;   // + row*512 + e
    const bf16* vbase = vT + (size_t)group * 64 * 1024;            // + d*1024 + key

    // staging coords (per thread, 2 chunks of 64-el rows)
    const int r0 = tid >> 3, e0 = (tid & 7) * 8;
    const int r1 = (256 + tid) >> 3;

    // ones A-fragment: A[row 0][k]=1.0 for all k, other rows 0
    const unsigned ow = (lm == 0) ? 0x3F803F80u : 0u;
    const u32x4 onesA = (u32x4){ow, ow, ow, ow};

    f32x4 accO[4][2];   // [d-tile][q-tile], O^T orientation
#pragma unroll
    for (int md = 0; md < 4; md++)
#pragma unroll
        for (int tm = 0; tm < 2; tm++) accO[md][tm] = (f32x4){0.f, 0.f, 0.f, 0.f};
    f32x4 accL[2] = {(f32x4){0.f, 0.f, 0.f, 0.f}, (f32x4){0.f, 0.f, 0.f, 0.f}};

    // prefetch kt=0
    u32x4 kreg0 = *(const u32x4*)&kbase[(size_t)r0 * 512 + e0];
    u32x4 kreg1 = *(const u32x4*)&kbase[(size_t)r1 * 512 + e0];
    u32x4 vreg0 = *(const u32x4*)&vbase[(size_t)r0 * 1024 + e0];
    u32x4 vreg1 = *(const u32x4*)&vbase[(size_t)r1 * 1024 + e0];

    for (int kt = 0; kt < 16; kt++) {
        bf16* Kb = Ks[kt & 1];
        bf16* Vb = Vs[kt & 1];
        *(u32x4*)&Kb[r0 * KP + e0] = kreg0;
        *(u32x4*)&Kb[r1 * KP + e0] = kreg1;
        *(u32x4*)&Vb[r0 * VP + e0] = vreg0;
        *(u32x4*)&Vb[r1 * VP + e0] = vreg1;
        __syncthreads();   // single barrier per K-tile (double-buffered)
        if (kt < 15) {     // prefetch: in flight across whole compute phase
            const bf16* kn = kbase + (size_t)((kt + 1) * 64) * 512;
            const bf16* vn = vbase + (kt + 1) * 64;
            kreg0 = *(const u32x4*)&kn[(size_t)r0 * 512 + e0];
            kreg1 = *(const u32x4*)&kn[(size_t)r1 * 512 + e0];
            vreg0 = *(const u32x4*)&vn[(size_t)r0 * 1024 + e0];
            vreg1 = *(const u32x4*)&vn[(size_t)r1 * 1024 + e0];
        }

#pragma unroll
        for (int kc = 0; kc < 2; kc++) {
            const int t0 = kc * 2;
            // S^T tiles for this 32-key contraction: A=K (m=key), B=Q (n=q)
            u32x4 kf00 = *(const u32x4*)&Kb[(t0 * 16 + lm) * KP + lq * 8];
            u32x4 kf01 = *(const u32x4*)&Kb[(t0 * 16 + lm) * KP + 32 + lq * 8];
            u32x4 kf10 = *(const u32x4*)&Kb[((t0 + 1) * 16 + lm) * KP + lq * 8];
            u32x4 kf11 = *(const u32x4*)&Kb[((t0 + 1) * 16 + lm) * KP + 32 + lq * 8];
            u32x4 pw[2];
#pragma unroll
            for (int tm = 0; tm < 2; tm++) {
                f32x4 s0 = (f32x4){0.f, 0.f, 0.f, 0.f};
                s0 = mfma16(kf00, qf[tm][0], s0);
                s0 = mfma16(kf01, qf[tm][1], s0);
                f32x4 s1 = (f32x4){0.f, 0.f, 0.f, 0.f};
                s1 = mfma16(kf10, qf[tm][0], s1);
                s1 = mfma16(kf11, qf[tm][1], s1);
                float p0 = __builtin_amdgcn_exp2f(s0[0]);
                float p1 = __builtin_amdgcn_exp2f(s0[1]);
                float p2 = __builtin_amdgcn_exp2f(s0[2]);
                float p3 = __builtin_amdgcn_exp2f(s0[3]);
                float p4 = __builtin_amdgcn_exp2f(s1[0]);
                float p5 = __builtin_amdgcn_exp2f(s1[1]);
                float p6 = __builtin_amdgcn_exp2f(s1[2]);
                float p7 = __builtin_amdgcn_exp2f(s1[3]);
                // slots 0-3 = tile t0 keys lq*4+r ; slots 4-7 = tile t0+1
                pw[tm] = (u32x4){trunc2(p0, p1), trunc2(p2, p3),
                                 trunc2(p4, p5), trunc2(p6, p7)};
            }
            // denominator: l += sum_k P (ones-row MFMA, off the VALU)
            accL[0] = mfma16(onesA, pw[0], accL[0]);
            accL[1] = mfma16(onesA, pw[1], accL[1]);
            // O^T += V^T * P^T : A = V^T from Vs (perm keys match pw slots)
            __builtin_amdgcn_s_setprio(1);
#pragma unroll
            for (int md = 0; md < 4; md++) {
                u32x4 vf = *(const u32x4*)&Vb[(md * 16 + lm) * VP + kc * 32 + lq * 8];
                accO[md][0] = mfma16(vf, pw[0], accO[md][0]);
                accO[md][1] = mfma16(vf, pw[1], accO[md][1]);
            }
            __builtin_amdgcn_s_setprio(0);
        }
    }

    // l lives in reg0 of lanes lq==0; xor-reduce over lq broadcasts to all.
#pragma unroll
    for (int tm = 0; tm < 2; tm++) {
        float l = accL[tm][0];
        l += __shfl_xor(l, 16);
        l += __shfl_xor(l, 32);
        float linv = 1.0f / l;
#pragma unroll
        for (int md = 0; md < 4; md++) {
            // row = q (lm), cols = hh*64 + md*16 + lq*4 .. +3 (8B bf16 store)
            *(unsigned long long*)&o[(size_t)(qrow0 + tm * 16 + lm) * 512 + hh * 64 + md * 16 + lq * 4] =
                pk4(accO[md][tm][0] * linv, accO[md][tm][1] * linv,
                    accO[md][tm][2] * linv, accO[md][tm][3] * linv);
        }
    }
}

// ------------- LayerNorm of (a + res), both bf16 -> bf16 out -----------------
// Used for ln#1: a = ob (attn out), res = xb (bf16 x, L3-resident). Reads
// 33 MB instead of 84 MB (f32 x dropped); vl is re-quantized bf16 anyway.
__global__ __launch_bounds__(256) void ln_bb(
    const bf16* __restrict__ a, const bf16* __restrict__ res,
    const float* __restrict__ g, const float* __restrict__ bb,
    bf16* __restrict__ out)
{
    int row = blockIdx.x * 4 + (threadIdx.x >> 6);
    int lane = threadIdx.x & 63;
    size_t base = (size_t)row * 512 + lane * 8;
    int cbase = lane * 8;

    bf8 av = __builtin_bit_cast(bf8, *(const u32x4*)&a[base]);
    bf8 rv = __builtin_bit_cast(bf8, *(const u32x4*)&res[base]);
    float x8[8];
#pragma unroll
    for (int i = 0; i < 8; i++)
        x8[i] = __bfloat162float(av.h[i]) + __bfloat162float(rv.h[i]);

    float s = 0.f, s2 = 0.f;
#pragma unroll
    for (int i = 0; i < 8; i++) { s += x8[i]; s2 += x8[i] * x8[i]; }
#pragma unroll
    for (int off = 1; off < 64; off <<= 1) {
        s += __shfl_xor(s, off);
        s2 += __shfl_xor(s2, off);
    }
    float mean = s * (1.f / 512.f);
    float var = s2 * (1.f / 512.f) - mean * mean;
    float rstd = rsqrtf(var + 1e-5f);

    f32x4 g0 = *(const f32x4*)&g[cbase], g1 = *(const f32x4*)&g[cbase + 4];
    f32x4 b0 = *(const f32x4*)&bb[cbase], b1v = *(const f32x4*)&bb[cbase + 4];
    bf8 ov;
#pragma unroll
    for (int i = 0; i < 4; i++) {
        ov.h[i] = __float2bfloat16((x8[i] - mean) * rstd * g0[i] + b0[i]);
        ov.h[4 + i] = __float2bfloat16((x8[4 + i] - mean) * rstd * g1[i] + b1v[i]);
    }
    *(u32x4*)&out[base] = __builtin_bit_cast(u32x4, ov);
}

// ------------- LayerNorm (one wave per 512-el row) — final LN ----------------
template <bool AF32, bool RES, bool OF32>
__global__ __launch_bounds__(256) void ln_kernel(
    const void* __restrict__ a, const float* __restrict__ res,
    const float* __restrict__ g, const float* __restrict__ bb, void* __restrict__ out)
{
    int row = blockIdx.x * 4 + (threadIdx.x >> 6);
    int lane = threadIdx.x & 63;
    size_t base = (size_t)row * 512 + lane * 8;
    int cbase = lane * 8;

    float x8[8];
    if (AF32) {
        const float* af = (const float*)a;
        f32x4 lo = *(const f32x4*)&af[base];
        f32x4 hi = *(const f32x4*)&af[base + 4];
#pragma unroll
        for (int i = 0; i < 4; i++) { x8[i] = lo[i]; x8[4 + i] = hi[i]; }
    } else {
        bf8 av = __builtin_bit_cast(bf8, *(const u32x4*)&((const bf16*)a)[base]);
#pragma unroll
        for (int i = 0; i < 8; i++) x8[i] = __bfloat162float(av.h[i]);
    }
    if (RES) {
        f32x4 lo = *(const f32x4*)&res[base];
        f32x4 hi = *(const f32x4*)&res[base + 4];
#pragma unroll
        for (int i = 0; i < 4; i++) { x8[i] += lo[i]; x8[4 + i] += hi[i]; }
    }

    float s = 0.f, s2 = 0.f;
#pragma unroll
    for (int i = 0; i < 8; i++) { s += x8[i]; s2 += x8[i] * x8[i]; }
#pragma unroll
    for (int off = 1; off < 64; off <<= 1) {
        s += __shfl_xor(s, off);
        s2 += __shfl_xor(s2, off);
    }
    float mean = s * (1.f / 512.f);
    float var = s2 * (1.f / 512.f) - mean * mean;
    float rstd = rsqrtf(var + 1e-5f);

    f32x4 g0 = *(const f32x4*)&g[cbase], g1 = *(const f32x4*)&g[cbase + 4];
    f32x4 b0 = *(const f32x4*)&bb[cbase], b1v = *(const f32x4*)&bb[cbase + 4];
    float y[8];
#pragma unroll
    for (int i = 0; i < 4; i++) {
        y[i] = (x8[i] - mean) * rstd * g0[i] + b0[i];
        y[4 + i] = (x8[4 + i] - mean) * rstd * g1[i] + b1v[i];
    }
    if (OF32) {
        float* op = (float*)out;
        *(f32x4*)&op[base] = (f32x4){y[0], y[1], y[2], y[3]};
        *(f32x4*)&op[base + 4] = (f32x4){y[4], y[5], y[6], y[7]};
    } else {
        bf8 ov;
#pragma unroll
        for (int i = 0; i < 8; i++) ov.h[i] = __float2bfloat16(y[i]);
        *(u32x4*)&((bf16*)out)[base] = __builtin_bit_cast(u32x4, ov);
    }
}

// ------------- launch --------------------------------------------------------
extern "C" void kernel_launch(void* const* d_in, const int* in_sizes, int n_in,
                              void* d_out, int out_size, void* d_ws, size_t ws_size,
                              hipStream_t stream)
{
    const float* x    = (const float*)d_in[0];
    const float* Wq   = (const float*)d_in[1];
    const float* bq   = (const float*)d_in[2];
    const float* Wk   = (const float*)d_in[3];
    const float* bk   = (const float*)d_in[4];
    const float* Wv   = (const float*)d_in[5];
    const float* bv   = (const float*)d_in[6];
    const float* ln_g = (const float*)d_in[7];
    const float* ln_b = (const float*)d_in[8];
    const float* W1   = (const float*)d_in[9];
    const float* b1   = (const float*)d_in[10];
    const float* W2   = (const float*)d_in[11];
    const float* b2   = (const float*)d_in[12];
    const float* lnffg = (const float*)d_in[13];
    const float* lnffb = (const float*)d_in[14];
    float* out = (float*)d_out;

    bf16* ws = (bf16*)d_ws;
    bf16* WT = ws;                        // 5 * 262144 bf16
    bf16* qb = ws + 5 * 262144;           // 8388608 bf16 each below
    bf16* kb = qb + 8388608;
    bf16* vT = kb + 8388608;
    bf16* vl = qb;                        // reuse (q dead after attention)
    bf16* f1 = kb;                        // reuse (k dead after attention)
    bf16* f2 = vT;                        // reuse (v dead after attention)
    // d_out (33,554,432 B) split: first half xb (8.4M bf16), second half ob.
    // xb read by gemm_qk/v AND as ln#1 residual; ob dead after ln#1;
    // final ln overwrites all of d_out.
    bf16* xb = (bf16*)d_out;
    bf16* ob = xb + 8388608;

    prep<<<4416, 256, 0, stream>>>(Wq, Wk, Wv, W1, W2, x, WT, xb);

    gemm_qk<<<dim3(128, 8), 256, 0, stream>>>(xb, WT, bq, bk, qb, kb);
    gemm_v <<<dim3(128, 8), 256, 0, stream>>>(xb, WT, bv, vT);

    attn_kernel<<<dim3(128, 8), 256, 0, stream>>>(qb, kb, vT, ob);

    ln_bb<<<4096, 256, 0, stream>>>(ob, xb, ln_g, ln_b, vl);

    dim3 gg(128, 8);
    gemm_bt<true> <<<gg, 256, 0, stream>>>(vl, WT + 3 * 262144, b1, f1);
    gemm_bt<false><<<gg, 256, 0, stream>>>(f1, WT + 4 * 262144, b2, f2);

    ln_kernel<false, false, true><<<4096, 256, 0, stream>>>(f2, nullptr, lnffg, lnffb, out);
}

// Round 15
// 235.318 us; speedup vs baseline: 1.0979x; 1.0186x over previous
//
#include <hip/hip_runtime.h>
#include <hip/hip_bf16.h>

using bf16 = __hip_bfloat16;
typedef unsigned int u32x4 __attribute__((ext_vector_type(4)));
typedef float f32x4 __attribute__((ext_vector_type(4)));
typedef __bf16 bf16x8 __attribute__((ext_vector_type(8)));

#define DEVI __device__ __forceinline__

DEVI f32x4 mfma16(u32x4 a, u32x4 b, f32x4 c) {
    return __builtin_amdgcn_mfma_f32_16x16x32_bf16(
        __builtin_bit_cast(bf16x8, a), __builtin_bit_cast(bf16x8, b), c, 0, 0, 0);
}

// async global->LDS DMA, 16B per lane; LDS dest = uniform base + lane*16
DEVI void gload16(const bf16* g, bf16* l) {
    __builtin_amdgcn_global_load_lds(
        (const __attribute__((address_space(1))) unsigned int*)g,
        (__attribute__((address_space(3))) unsigned int*)l,
        16, 0, 0);
}

struct bf8 { bf16 h[8]; };

DEVI u32x4 pack8(f32x4 lo, f32x4 hi) {
    bf8 t;
#pragma unroll
    for (int i = 0; i < 4; i++) {
        t.h[i] = __float2bfloat16(lo[i]);
        t.h[4 + i] = __float2bfloat16(hi[i]);
    }
    return __builtin_bit_cast(u32x4, t);
}

// RNE-packed 4x bf16 -> 64-bit
DEVI unsigned long long pk4(float a, float b, float c, float d) {
    union { unsigned long long u; bf16 h[4]; } t;
    t.h[0] = __float2bfloat16(a); t.h[1] = __float2bfloat16(b);
    t.h[2] = __float2bfloat16(c); t.h[3] = __float2bfloat16(d);
    return t.u;
}

// truncating bf16x2 pack (1 op)
DEVI unsigned trunc2(float a, float b) {
    return __builtin_amdgcn_perm(__builtin_bit_cast(unsigned, b),
                                 __builtin_bit_cast(unsigned, a), 0x07060302);
}

// ------------- prep: WT[n][k] = (bf16)W[k][n] via LDS-tiled transpose --------
// W-transpose: 64x64 f32 tiles through LDS T[64][65] — global read and
// transposed write both 256B/wave coalesced; pad-65 kills LDS conflicts.
// Blocks 0..319: 5 matrices x 64 tiles. Blocks 320+: xb = (bf16)x at
// 16 f32/thread (64B/lane reads — round-15: halves block count, 2x ILP).
__global__ __launch_bounds__(256) void prep(
    const float* __restrict__ Wq, const float* __restrict__ Wk,
    const float* __restrict__ Wv, const float* __restrict__ W1,
    const float* __restrict__ W2, const float* __restrict__ x,
    bf16* __restrict__ WT, bf16* __restrict__ xb)
{
    __shared__ float T[64][65];
    int b = blockIdx.x;
    if (b < 320) {
        int w = b >> 6;                 // matrix 0..4
        int t = b & 63;                 // tile 0..63
        int kk0 = (t >> 3) * 64, n0 = (t & 7) * 64;
        const float* src = (w == 0) ? Wq : (w == 1) ? Wk : (w == 2) ? Wv : (w == 3) ? W1 : W2;
        const int r4 = threadIdx.x >> 6;    // wave id 0..3 (row offset)
        const int c = threadIdx.x & 63;     // lane
#pragma unroll
        for (int p = 0; p < 16; p++) {
            int row = p * 4 + r4;
            T[row][c] = src[(size_t)(kk0 + row) * 512 + n0 + c];
        }
        __syncthreads();
#pragma unroll
        for (int p = 0; p < 16; p++) {
            int nrow = p * 4 + r4;
            WT[(size_t)w * 262144 + (size_t)(n0 + nrow) * 512 + kk0 + c] =
                __float2bfloat16(T[c][nrow]);
        }
    } else {
        size_t i = ((size_t)(b - 320) * 256 + threadIdx.x) * 16;
        f32x4 a0 = *(const f32x4*)&x[i];
        f32x4 a1 = *(const f32x4*)&x[i + 4];
        f32x4 a2 = *(const f32x4*)&x[i + 8];
        f32x4 a3 = *(const f32x4*)&x[i + 12];
        *(u32x4*)&xb[i] = pack8(a0, a1);
        *(u32x4*)&xb[i + 8] = pack8(a2, a3);
    }
}

// ------------- GEMM cores: global_load_lds staging, XOR-swizzled LDS ---------
// LDS LINEAR (gload_lds writes lane-linear; padding forbidden). Conflict-free
// via XOR swizzle applied BOTH sides (rule 21):
//   write: per-lane global col = ((lane&7) ^ (lane>>3))*8
//   read : col ^= (lm&7)*8    (row&7 == lm&7 for every fragment row)
// DISCIPLINE (rounds 2-4,8,11,12 post-mortems):
//   * one body per kernel; no min-waves launch_bounds arg; no explicit LDS dbuf
//   * do NOT fuse LN into attn (r11) and do NOT shrink attn q-tiles (r12):
//     staging amortization per q-row is the binding quantity.
#define GEMM_BODY(EPILOGUE)                                                          \
    __shared__ __align__(16) bf16 As[128 * 64];                                      \
    __shared__ __align__(16) bf16 Bs[128 * 64];                                      \
    const int tid = threadIdx.x;                                                     \
    const int lane = tid & 63, wave = tid >> 6;                                      \
    const int wm = (wave >> 1) * 64, wn = (wave & 1) * 64;                           \
    const int lm = lane & 15, lq = lane >> 4;                                        \
    const int cxor = (lm & 7) * 8;                                                   \
    const int srow = wave * 32 + (lane >> 3);                                        \
    const int scol = ((lane & 7) ^ (lane >> 3)) * 8;                                 \
    const bf16* Ag = A + (size_t)(bm + srow) * 512 + scol;                           \
    const bf16* Bg = Bt + (size_t)(bn + srow) * 512 + scol;                          \
    bf16* Al = &As[wave * 32 * 64];                                                  \
    bf16* Bl = &Bs[wave * 32 * 64];                                                  \
    f32x4 acc[4][4];                                                                 \
    _Pragma("unroll") for (int i = 0; i < 4; i++)                                    \
        _Pragma("unroll") for (int j = 0; j < 4; j++)                                \
            acc[i][j] = (f32x4){0.f, 0.f, 0.f, 0.f};                                 \
    for (int k0 = 0; k0 < 512; k0 += 64) {                                           \
        __syncthreads();                                                             \
        _Pragma("unroll") for (int p = 0; p < 4; p++) {                              \
            gload16(Ag + (size_t)p * 8 * 512 + k0, Al + p * 512);                    \
            gload16(Bg + (size_t)p * 8 * 512 + k0, Bl + p * 512);                    \
        }                                                                            \
        __syncthreads();                                                             \
        _Pragma("unroll") for (int h = 0; h < 2; h++) {                              \
            u32x4 af[4], bfr[4];                                                     \
            _Pragma("unroll") for (int i = 0; i < 4; i++)                            \
                af[i] = *(const u32x4*)&As[(wm + i * 16 + lm) * 64 + ((h * 32 + lq * 8) ^ cxor)]; \
            _Pragma("unroll") for (int j = 0; j < 4; j++)                            \
                bfr[j] = *(const u32x4*)&Bs[(wn + j * 16 + lm) * 64 + ((h * 32 + lq * 8) ^ cxor)]; \
            EPILOGUE##_MMA                                                           \
        }                                                                            \
    }

#define SWAPPED_MMA                                                                  \
    _Pragma("unroll") for (int i = 0; i < 4; i++)                                    \
        _Pragma("unroll") for (int j = 0; j < 4; j++)                                \
            acc[i][j] = mfma16(bfr[j], af[i], acc[i][j]);

#define GEMM_BODY_N64(EPILOGUE)                                                      \
    __shared__ __align__(16) bf16 As[128 * 64];                                      \
    __shared__ __align__(16) bf16 Bs[64 * 64];                                       \
    const int tid = threadIdx.x;                                                     \
    const int lane = tid & 63, wave = tid >> 6;                                      \
    const int wm = wave * 32;                                                        \
    const int lm = lane & 15, lq = lane >> 4;                                        \
    const int cxor = (lm & 7) * 8;                                                   \
    const int sr8 = lane >> 3;                                                       \
    const int scol = ((lane & 7) ^ sr8) * 8;                                         \
    const bf16* Ag = A + (size_t)(bm + wave * 32 + sr8) * 512 + scol;                \
    const bf16* Bg = Bt + (size_t)(bn + wave * 16 + sr8) * 512 + scol;               \
    bf16* Al = &As[wave * 32 * 64];                                                  \
    bf16* Bl = &Bs[wave * 16 * 64];                                                  \
    f32x4 acc[2][4];                                                                 \
    _Pragma("unroll") for (int i = 0; i < 2; i++)                                    \
        _Pragma("unroll") for (int j = 0; j < 4; j++)                                \
            acc[i][j] = (f32x4){0.f, 0.f, 0.f, 0.f};                                 \
    for (int k0 = 0; k0 < 512; k0 += 64) {                                           \
        __syncthreads();                                                             \
        _Pragma("unroll") for (int p = 0; p < 4; p++)                                \
            gload16(Ag + (size_t)p * 8 * 512 + k0, Al + p * 512);                    \
        _Pragma("unroll") for (int p = 0; p < 2; p++)                                \
            gload16(Bg + (size_t)p * 8 * 512 + k0, Bl + p * 512);                    \
        __syncthreads();                                                             \
        _Pragma("unroll") for (int h = 0; h < 2; h++) {                              \
            u32x4 af[2], bfr[4];                                                     \
            _Pragma("unroll") for (int i = 0; i < 2; i++)                            \
                af[i] = *(const u32x4*)&As[(wm + i * 16 + lm) * 64 + ((h * 32 + lq * 8) ^ cxor)]; \
            _Pragma("unroll") for (int j = 0; j < 4; j++)                            \
                bfr[j] = *(const u32x4*)&Bs[(j * 16 + lm) * 64 + ((h * 32 + lq * 8) ^ cxor)]; \
            EPILOGUE##_MMA_N64                                                       \
        }                                                                            \
    }

#define SWAPPED_MMA_N64                                                              \
    _Pragma("unroll") for (int i = 0; i < 2; i++)                                    \
        _Pragma("unroll") for (int j = 0; j < 4; j++)                                \
            acc[i][j] = mfma16(bfr[j], af[i], acc[i][j]);
#define NORMAL_MMA_N64                                                               \
    _Pragma("unroll") for (int i = 0; i < 2; i++)                                    \
        _Pragma("unroll") for (int j = 0; j < 4; j++)                                \
            acc[i][j] = mfma16(af[i], bfr[j], acc[i][j]);

// ------------- Q/K GEMM (swapped orientation), 128x128, 4 blk/CU -------------
__global__ __launch_bounds__(256) void gemm_qk(
    const bf16* __restrict__ A, const bf16* __restrict__ WT,
    const float* __restrict__ bqp, const float* __restrict__ bkp,
    bf16* __restrict__ qb, bf16* __restrict__ kb)
{
    const int wsel = blockIdx.y >> 2;                  // 0=q 1=k
    const int bm = blockIdx.x * 128, bn = (blockIdx.y & 3) * 128;
    const bf16* Bt = WT + (size_t)wsel * 262144;
    const float* bias = (wsel == 0) ? bqp : bkp;
    const float scale = (wsel == 0) ? 0.18033688f : 1.0f;   // log2e/8 into q
    bf16* dst = (wsel == 0) ? qb : kb;

    GEMM_BODY(SWAPPED)
#pragma unroll
    for (int i = 0; i < 4; i++) {
#pragma unroll
        for (int j = 0; j < 4; j++) {
            int row = bm + wm + i * 16 + lm;
            int colb = bn + wn + j * 16 + lq * 4;
            f32x4 b4 = *(const f32x4*)&bias[colb];
            *(unsigned long long*)&dst[(size_t)row * 512 + colb] =
                pk4((acc[i][j][0] + b4[0]) * scale, (acc[i][j][1] + b4[1]) * scale,
                    (acc[i][j][2] + b4[2]) * scale, (acc[i][j][3] + b4[3]) * scale);
        }
    }
}

// ------------- V GEMM (normal orientation) -> vT pack, 128x64 tile -----------
// vT key permutation (consumed by attn PV as the MFMA k-slot order):
//   within each 32-key block, key u = 16h + 4a + t  (h:1b, a:2b, t:2b)
//   is stored at column cc = 8a + 4h + t.
__global__ __launch_bounds__(256) void gemm_v(
    const bf16* __restrict__ A, const bf16* __restrict__ WT,
    const float* __restrict__ bvp, bf16* __restrict__ vT)
{
    const int bm = blockIdx.x * 128, bn = blockIdx.y * 64;
    const bf16* Bt = WT + (size_t)2 * 262144;
    const float* bias = bvp;

    GEMM_BODY_N64(NORMAL)
#pragma unroll
    for (int i = 0; i < 2; i++) {
#pragma unroll
        for (int j = 0; j < 4; j++) {
            int col = bn + j * 16 + lm;
            float bv = bias[col];
            int rowb = bm + wm + i * 16 + lq * 4;   // 4 consecutive nodes (mult of 4)
            int btq = rowb >> 10, node = rowb & 1023;
            int u = node & 31;                      // u&3 == 0 always
            int nodeP = (node & ~31) | (((u >> 2) & 3) << 3) | (((u >> 4) & 1) << 2);
            *(unsigned long long*)&vT[((size_t)((btq * 8 + (col >> 6)) * 64 + (col & 63))) * 1024 + nodeP] =
                pk4(acc[i][j][0] + bv, acc[i][j][1] + bv,
                    acc[i][j][2] + bv, acc[i][j][3] + bv);
        }
    }
}

// ------------- FFN GEMM (RELU or plain), swapped, 128x64 tile ----------------
template <bool RELU>
__global__ __launch_bounds__(256) void gemm_bt(
    const bf16* __restrict__ A, const bf16* __restrict__ Bt,
    const float* __restrict__ bias, bf16* __restrict__ C)
{
    const int bm = blockIdx.x * 128, bn = blockIdx.y * 64;
    GEMM_BODY_N64(SWAPPED)
#pragma unroll
    for (int i = 0; i < 2; i++) {
#pragma unroll
        for (int j = 0; j < 4; j++) {
            int row = bm + wm + i * 16 + lm;
            int colb = bn + j * 16 + lq * 4;
            f32x4 b4 = *(const f32x4*)&bias[colb];
            float c0 = acc[i][j][0] + b4[0], c1 = acc[i][j][1] + b4[1];
            float c2 = acc[i][j][2] + b4[2], c3 = acc[i][j][3] + b4[3];
            if (RELU) {
                c0 = fmaxf(c0, 0.f); c1 = fmaxf(c1, 0.f);
                c2 = fmaxf(c2, 0.f); c3 = fmaxf(c3, 0.f);
            }
            *(unsigned long long*)&C[(size_t)row * 512 + colb] = pk4(c0, c1, c2, c3);
        }
    }
}

// ------------- flash attention: register-P, O^T = V^T * P^T ------------------
// Round-9 proven config: 128-row q-tiles, double-buffered K/V LDS (36,864 B),
// ONE barrier per K-tile, register prefetch across compute; o stored bf16.
// ~813 TF-equivalent (34.4 GF / 42.3 us) = at the 2-barrier structural
// ceiling; MFMA+VALU combined issue ~73% (VALU half is irreducible exp2).
// q (pre-scaled by log2e/8), k: [16384 x 512] bf16
// vT: [(g)*64+d][1024] bf16, keys PERMUTED within 32-blocks (see gemm_v).
// o: [16384 x 512] bf16.  grid(128 groups, 8 qtiles of 128 rows), 256 thr.
__global__ __launch_bounds__(256, 4) void attn_kernel(
    const bf16* __restrict__ q, const bf16* __restrict__ k,
    const bf16* __restrict__ vT, bf16* __restrict__ o)
{
    constexpr int KP = 72;   // 144 B stride: 16-B aligned, free 2-way
    constexpr int VP = 72;
    __shared__ __align__(16) bf16 Ks[2][64 * KP];     // [buf][key][d]
    __shared__ __align__(16) bf16 Vs[2][64 * VP];     // [buf][d][perm-key]

    const int tid = threadIdx.x, lane = tid & 63, wave = tid >> 6;
    const int group = blockIdx.x;          // bt*8 + h
    const int bt = group >> 3, hh = group & 7;
    const int lm = lane & 15, lq = lane >> 4;
    const int qrow0 = bt * 1024 + blockIdx.y * 128 + wave * 32;

    u32x4 qf[2][2];
#pragma unroll
    for (int tm = 0; tm < 2; tm++)
#pragma unroll
        for (int kk2 = 0; kk2 < 2; kk2++)
            qf[tm][kk2] = *(const u32x4*)&q[(size_t)(qrow0 + tm * 16 + lm) * 512 + hh * 64 + kk2 * 32 + lq * 8];

    const bf16* kbase = k + (size_t)(bt * 1024) * 512 + hh * 64;   // + row*512 + e
    const bf16* vbase = vT + (size_t)group * 64 * 1024;            // + d*1024 + key

    // staging coords (per thread, 2 chunks of 64-el rows)
    const int r0 = tid >> 3, e0 = (tid & 7) * 8;
    const int r1 = (256 + tid) >> 3;

    // ones A-fragment: A[row 0][k]=1.0 for all k, other rows 0
    const unsigned ow = (lm == 0) ? 0x3F803F80u : 0u;
    const u32x4 onesA = (u32x4){ow, ow, ow, ow};

    f32x4 accO[4][2];   // [d-tile][q-tile], O^T orientation
#pragma unroll
    for (int md = 0; md < 4; md++)
#pragma unroll
        for (int tm = 0; tm < 2; tm++) accO[md][tm] = (f32x4){0.f, 0.f, 0.f, 0.f};
    f32x4 accL[2] = {(f32x4){0.f, 0.f, 0.f, 0.f}, (f32x4){0.f, 0.f, 0.f, 0.f}};

    // prefetch kt=0
    u32x4 kreg0 = *(const u32x4*)&kbase[(size_t)r0 * 512 + e0];
    u32x4 kreg1 = *(const u32x4*)&kbase[(size_t)r1 * 512 + e0];
    u32x4 vreg0 = *(const u32x4*)&vbase[(size_t)r0 * 1024 + e0];
    u32x4 vreg1 = *(const u32x4*)&vbase[(size_t)r1 * 1024 + e0];

    for (int kt = 0; kt < 16; kt++) {
        bf16* Kb = Ks[kt & 1];
        bf16* Vb = Vs[kt & 1];
        *(u32x4*)&Kb[r0 * KP + e0] = kreg0;
        *(u32x4*)&Kb[r1 * KP + e0] = kreg1;
        *(u32x4*)&Vb[r0 * VP + e0] = vreg0;
        *(u32x4*)&Vb[r1 * VP + e0] = vreg1;
        __syncthreads();   // single barrier per K-tile (double-buffered)
        if (kt < 15) {     // prefetch: in flight across whole compute phase
            const bf16* kn = kbase + (size_t)((kt + 1) * 64) * 512;
            const bf16* vn = vbase + (kt + 1) * 64;
            kreg0 = *(const u32x4*)&kn[(size_t)r0 * 512 + e0];
            kreg1 = *(const u32x4*)&kn[(size_t)r1 * 512 + e0];
            vreg0 = *(const u32x4*)&vn[(size_t)r0 * 1024 + e0];
            vreg1 = *(const u32x4*)&vn[(size_t)r1 * 1024 + e0];
        }

#pragma unroll
        for (int kc = 0; kc < 2; kc++) {
            const int t0 = kc * 2;
            // S^T tiles for this 32-key contraction: A=K (m=key), B=Q (n=q)
            u32x4 kf00 = *(const u32x4*)&Kb[(t0 * 16 + lm) * KP + lq * 8];
            u32x4 kf01 = *(const u32x4*)&Kb[(t0 * 16 + lm) * KP + 32 + lq * 8];
            u32x4 kf10 = *(const u32x4*)&Kb[((t0 + 1) * 16 + lm) * KP + lq * 8];
            u32x4 kf11 = *(const u32x4*)&Kb[((t0 + 1) * 16 + lm) * KP + 32 + lq * 8];
            u32x4 pw[2];
#pragma unroll
            for (int tm = 0; tm < 2; tm++) {
                f32x4 s0 = (f32x4){0.f, 0.f, 0.f, 0.f};
                s0 = mfma16(kf00, qf[tm][0], s0);
                s0 = mfma16(kf01, qf[tm][1], s0);
                f32x4 s1 = (f32x4){0.f, 0.f, 0.f, 0.f};
                s1 = mfma16(kf10, qf[tm][0], s1);
                s1 = mfma16(kf11, qf[tm][1], s1);
                float p0 = __builtin_amdgcn_exp2f(s0[0]);
                float p1 = __builtin_amdgcn_exp2f(s0[1]);
                float p2 = __builtin_amdgcn_exp2f(s0[2]);
                float p3 = __builtin_amdgcn_exp2f(s0[3]);
                float p4 = __builtin_amdgcn_exp2f(s1[0]);
                float p5 = __builtin_amdgcn_exp2f(s1[1]);
                float p6 = __builtin_amdgcn_exp2f(s1[2]);
                float p7 = __builtin_amdgcn_exp2f(s1[3]);
                // slots 0-3 = tile t0 keys lq*4+r ; slots 4-7 = tile t0+1
                pw[tm] = (u32x4){trunc2(p0, p1), trunc2(p2, p3),
                                 trunc2(p4, p5), trunc2(p6, p7)};
            }
            // denominator: l += sum_k P (ones-row MFMA, off the VALU)
            accL[0] = mfma16(onesA, pw[0], accL[0]);
            accL[1] = mfma16(onesA, pw[1], accL[1]);
            // O^T += V^T * P^T : A = V^T from Vs (perm keys match pw slots)
            __builtin_amdgcn_s_setprio(1);
#pragma unroll
            for (int md = 0; md < 4; md++) {
                u32x4 vf = *(const u32x4*)&Vb[(md * 16 + lm) * VP + kc * 32 + lq * 8];
                accO[md][0] = mfma16(vf, pw[0], accO[md][0]);
                accO[md][1] = mfma16(vf, pw[1], accO[md][1]);
            }
            __builtin_amdgcn_s_setprio(0);
        }
    }

    // l lives in reg0 of lanes lq==0; xor-reduce over lq broadcasts to all.
#pragma unroll
    for (int tm = 0; tm < 2; tm++) {
        float l = accL[tm][0];
        l += __shfl_xor(l, 16);
        l += __shfl_xor(l, 32);
        float linv = 1.0f / l;
#pragma unroll
        for (int md = 0; md < 4; md++) {
            // row = q (lm), cols = hh*64 + md*16 + lq*4 .. +3 (8B bf16 store)
            *(unsigned long long*)&o[(size_t)(qrow0 + tm * 16 + lm) * 512 + hh * 64 + md * 16 + lq * 4] =
                pk4(accO[md][tm][0] * linv, accO[md][tm][1] * linv,
                    accO[md][tm][2] * linv, accO[md][tm][3] * linv);
        }
    }
}

// ------------- LayerNorm of (a + res), both bf16 -> bf16 out, 2 rows/wave ----
// ln#1: a = ob (attn out), res = xb (bf16 x, L3-resident). 2 rows per wave
// (round-15): doubles loads-in-flight per wave, halves block count.
__global__ __launch_bounds__(256) void ln_bb(
    const bf16* __restrict__ a, const bf16* __restrict__ res,
    const float* __restrict__ g, const float* __restrict__ bb,
    bf16* __restrict__ out)
{
    int row0 = (blockIdx.x * 4 + (threadIdx.x >> 6)) * 2;
    int lane = threadIdx.x & 63;
    int cbase = lane * 8;
    size_t base0 = (size_t)row0 * 512 + cbase;
    size_t base1 = base0 + 512;

    bf8 a0 = __builtin_bit_cast(bf8, *(const u32x4*)&a[base0]);
    bf8 a1 = __builtin_bit_cast(bf8, *(const u32x4*)&a[base1]);
    bf8 r0 = __builtin_bit_cast(bf8, *(const u32x4*)&res[base0]);
    bf8 r1 = __builtin_bit_cast(bf8, *(const u32x4*)&res[base1]);
    float x0[8], x1[8];
#pragma unroll
    for (int i = 0; i < 8; i++) {
        x0[i] = __bfloat162float(a0.h[i]) + __bfloat162float(r0.h[i]);
        x1[i] = __bfloat162float(a1.h[i]) + __bfloat162float(r1.h[i]);
    }

    float s0 = 0.f, q0 = 0.f, s1 = 0.f, q1 = 0.f;
#pragma unroll
    for (int i = 0; i < 8; i++) {
        s0 += x0[i]; q0 += x0[i] * x0[i];
        s1 += x1[i]; q1 += x1[i] * x1[i];
    }
#pragma unroll
    for (int off = 1; off < 64; off <<= 1) {
        s0 += __shfl_xor(s0, off); q0 += __shfl_xor(q0, off);
        s1 += __shfl_xor(s1, off); q1 += __shfl_xor(q1, off);
    }
    float m0 = s0 * (1.f / 512.f), m1 = s1 * (1.f / 512.f);
    float rs0 = rsqrtf(q0 * (1.f / 512.f) - m0 * m0 + 1e-5f);
    float rs1 = rsqrtf(q1 * (1.f / 512.f) - m1 * m1 + 1e-5f);

    f32x4 g0 = *(const f32x4*)&g[cbase], g1 = *(const f32x4*)&g[cbase + 4];
    f32x4 b0 = *(const f32x4*)&bb[cbase], b1v = *(const f32x4*)&bb[cbase + 4];
    bf8 o0, o1;
#pragma unroll
    for (int i = 0; i < 4; i++) {
        o0.h[i] = __float2bfloat16((x0[i] - m0) * rs0 * g0[i] + b0[i]);
        o0.h[4 + i] = __float2bfloat16((x0[4 + i] - m0) * rs0 * g1[i] + b1v[i]);
        o1.h[i] = __float2bfloat16((x1[i] - m1) * rs1 * g0[i] + b0[i]);
        o1.h[4 + i] = __float2bfloat16((x1[4 + i] - m1) * rs1 * g1[i] + b1v[i]);
    }
    *(u32x4*)&out[base0] = __builtin_bit_cast(u32x4, o0);
    *(u32x4*)&out[base1] = __builtin_bit_cast(u32x4, o1);
}

// ------------- final LayerNorm: bf16 in -> f32 out, 2 rows/wave --------------
__global__ __launch_bounds__(256) void ln_f(
    const bf16* __restrict__ a, const float* __restrict__ g,
    const float* __restrict__ bb, float* __restrict__ out)
{
    int row0 = (blockIdx.x * 4 + (threadIdx.x >> 6)) * 2;
    int lane = threadIdx.x & 63;
    int cbase = lane * 8;
    size_t base0 = (size_t)row0 * 512 + cbase;
    size_t base1 = base0 + 512;

    bf8 a0 = __builtin_bit_cast(bf8, *(const u32x4*)&a[base0]);
    bf8 a1 = __builtin_bit_cast(bf8, *(const u32x4*)&a[base1]);
    float x0[8], x1[8];
#pragma unroll
    for (int i = 0; i < 8; i++) {
        x0[i] = __bfloat162float(a0.h[i]);
        x1[i] = __bfloat162float(a1.h[i]);
    }

    float s0 = 0.f, q0 = 0.f, s1 = 0.f, q1 = 0.f;
#pragma unroll
    for (int i = 0; i < 8; i++) {
        s0 += x0[i]; q0 += x0[i] * x0[i];
        s1 += x1[i]; q1 += x1[i] * x1[i];
    }
#pragma unroll
    for (int off = 1; off < 64; off <<= 1) {
        s0 += __shfl_xor(s0, off); q0 += __shfl_xor(q0, off);
        s1 += __shfl_xor(s1, off); q1 += __shfl_xor(q1, off);
    }
    float m0 = s0 * (1.f / 512.f), m1 = s1 * (1.f / 512.f);
    float rs0 = rsqrtf(q0 * (1.f / 512.f) - m0 * m0 + 1e-5f);
    float rs1 = rsqrtf(q1 * (1.f / 512.f) - m1 * m1 + 1e-5f);

    f32x4 g0 = *(const f32x4*)&g[cbase], g1 = *(const f32x4*)&g[cbase + 4];
    f32x4 b0 = *(const f32x4*)&bb[cbase], b1v = *(const f32x4*)&bb[cbase + 4];
    f32x4 y;
#pragma unroll
    for (int i = 0; i < 4; i++) y[i] = (x0[i] - m0) * rs0 * g0[i] + b0[i];
    *(f32x4*)&out[base0] = y;
#pragma unroll
    for (int i = 0; i < 4; i++) y[i] = (x0[4 + i] - m0) * rs0 * g1[i] + b1v[i];
    *(f32x4*)&out[base0 + 4] = y;
#pragma unroll
    for (int i = 0; i < 4; i++) y[i] = (x1[i] - m1) * rs1 * g0[i] + b0[i];
    *(f32x4*)&out[base1] = y;
#pragma unroll
    for (int i = 0; i < 4; i++) y[i] = (x1[4 + i] - m1) * rs1 * g1[i] + b1v[i];
    *(f32x4*)&out[base1 + 4] = y;
}

// ------------- launch --------------------------------------------------------
extern "C" void kernel_launch(void* const* d_in, const int* in_sizes, int n_in,
                              void* d_out, int out_size, void* d_ws, size_t ws_size,
                              hipStream_t stream)
{
    const float* x    = (const float*)d_in[0];
    const float* Wq   = (const float*)d_in[1];
    const float* bq   = (const float*)d_in[2];
    const float* Wk   = (const float*)d_in[3];
    const float* bk   = (const float*)d_in[4];
    const float* Wv   = (const float*)d_in[5];
    const float* bv   = (const float*)d_in[6];
    const float* ln_g = (const float*)d_in[7];
    const float* ln_b = (const float*)d_in[8];
    const float* W1   = (const float*)d_in[9];
    const float* b1   = (const float*)d_in[10];
    const float* W2   = (const float*)d_in[11];
    const float* b2   = (const float*)d_in[12];
    const float* lnffg = (const float*)d_in[13];
    const float* lnffb = (const float*)d_in[14];
    float* out = (float*)d_out;

    bf16* ws = (bf16*)d_ws;
    bf16* WT = ws;                        // 5 * 262144 bf16
    bf16* qb = ws + 5 * 262144;           // 8388608 bf16 each below
    bf16* kb = qb + 8388608;
    bf16* vT = kb + 8388608;
    bf16* vl = qb;                        // reuse (q dead after attention)
    bf16* f1 = kb;                        // reuse (k dead after attention)
    bf16* f2 = vT;                        // reuse (v dead after attention)
    // d_out (33,554,432 B) split: first half xb (8.4M bf16), second half ob.
    // xb read by gemm_qk/v AND as ln#1 residual; ob dead after ln#1;
    // final ln overwrites all of d_out.
    bf16* xb = (bf16*)d_out;
    bf16* ob = xb + 8388608;

    prep<<<2368, 256, 0, stream>>>(Wq, Wk, Wv, W1, W2, x, WT, xb);

    gemm_qk<<<dim3(128, 8), 256, 0, stream>>>(xb, WT, bq, bk, qb, kb);
    gemm_v <<<dim3(128, 8), 256, 0, stream>>>(xb, WT, bv, vT);

    attn_kernel<<<dim3(128, 8), 256, 0, stream>>>(qb, kb, vT, ob);

    ln_bb<<<2048, 256, 0, stream>>>(ob, xb, ln_g, ln_b, vl);

    dim3 gg(128, 8);
    gemm_bt<true> <<<gg, 256, 0, stream>>>(vl, WT + 3 * 262144, b1, f1);
    gemm_bt<false><<<gg, 256, 0, stream>>>(f1, WT + 4 * 262144, b2, f2);

    ln_f<<<2048, 256, 0, stream>>>(f2, lnffg, lnffb, out);
}